// Round 4
// baseline (1026.464 us; speedup 1.0000x reference)
//
#include <hip/hip_runtime.h>
#include <hip/hip_bf16.h>

#define NN 6144
#define FEATN 128
#define INSM 512
#define HIDN 256
#define DOUT 64

// ---------------------------------------------------------------------------
// Branch MLPs: out = prelu(X@W0+b0, a) @ W1 + b1.   (outputs FLOAT32)
// blockIdx.y: 0 = local(ori)->out0, 1 = smooth->out1, 2 = hete->emb, ut (ws)
// br==2 writes u TRANSPOSED: ut[64][6144] (ut[c][i] = u[i][c]).
// ---------------------------------------------------------------------------
__global__ __launch_bounds__(256) void mlp_kernel(
    const float* __restrict__ ori, const float* __restrict__ sm,
    const float* __restrict__ W0s, const float* __restrict__ b0s,
    const float* __restrict__ W1s, const float* __restrict__ b1s,
    const float* __restrict__ W0l, const float* __restrict__ b0l,
    const float* __restrict__ W1l, const float* __restrict__ b1l,
    const float* __restrict__ W0h, const float* __restrict__ b0h,
    const float* __restrict__ W1h, const float* __restrict__ b1h,
    const float* __restrict__ am_p, const float* __restrict__ ah_p,
    float* __restrict__ out, float* __restrict__ emb, float* __restrict__ ut)
{
    __shared__ float xs[8 * INSM];
    __shared__ float hs[8 * HIDN];
    __shared__ float vals[8 * DOUT];
    const int t = threadIdx.x;
    const int br = blockIdx.y;
    const int r0 = blockIdx.x * 8;

    const float *X, *W0, *b0, *W1, *b1;
    int IN;
    float alpha;
    if (br == 0)      { X = ori; W0 = W0l; b0 = b0l; W1 = W1l; b1 = b1l; IN = FEATN; alpha = am_p[0]; }
    else if (br == 1) { X = sm;  W0 = W0s; b0 = b0s; W1 = W1s; b1 = b1s; IN = INSM;  alpha = am_p[0]; }
    else              { X = sm;  W0 = W0h; b0 = b0h; W1 = W1h; b1 = b1h; IN = INSM;  alpha = ah_p[0]; }

    const float* Xb = X + (size_t)r0 * IN;
    const int tot4 = (8 * IN) >> 2;
    for (int i = t; i < tot4; i += 256)
        reinterpret_cast<float4*>(xs)[i] = reinterpret_cast<const float4*>(Xb)[i];
    __syncthreads();

    float acc[8];
    #pragma unroll
    for (int r = 0; r < 8; ++r) acc[r] = 0.f;
    for (int k = 0; k < IN; k += 4) {
        const float w0 = W0[(k + 0) * HIDN + t];
        const float w1 = W0[(k + 1) * HIDN + t];
        const float w2 = W0[(k + 2) * HIDN + t];
        const float w3 = W0[(k + 3) * HIDN + t];
        #pragma unroll
        for (int r = 0; r < 8; ++r) {
            float4 x4 = *reinterpret_cast<const float4*>(&xs[r * IN + k]);
            acc[r] = fmaf(x4.x, w0, acc[r]);
            acc[r] = fmaf(x4.y, w1, acc[r]);
            acc[r] = fmaf(x4.z, w2, acc[r]);
            acc[r] = fmaf(x4.w, w3, acc[r]);
        }
    }
    {
        float bb = b0[t];
        #pragma unroll
        for (int r = 0; r < 8; ++r) {
            float h = acc[r] + bb;
            hs[r * HIDN + t] = (h >= 0.f) ? h : alpha * h;
        }
    }
    __syncthreads();

    for (int task = t; task < 512; task += 256) {
        const int r = task >> 6, c = task & 63;
        float a2 = b1[c];
        for (int k = 0; k < HIDN; k += 4) {
            float4 h4 = *reinterpret_cast<const float4*>(&hs[r * HIDN + k]);
            a2 = fmaf(h4.x, W1[(k + 0) * DOUT + c], a2);
            a2 = fmaf(h4.y, W1[(k + 1) * DOUT + c], a2);
            a2 = fmaf(h4.z, W1[(k + 2) * DOUT + c], a2);
            a2 = fmaf(h4.w, W1[(k + 3) * DOUT + c], a2);
        }
        if (br < 2) {
            float* dst = out + (size_t)br * NN * DOUT;
            dst[(size_t)(r0 + r) * DOUT + c] = a2;
        } else {
            vals[r * DOUT + c] = a2;
        }
    }
    if (br == 2) {
        __syncthreads();
        const int wv = t >> 6, lane = t & 63;
        #pragma unroll
        for (int rep = 0; rep < 2; ++rep) {
            const int row = wv * 2 + rep;
            float v = vals[row * DOUT + lane];
            float mv = v;
            for (int off = 32; off > 0; off >>= 1) mv = fmaxf(mv, __shfl_xor(mv, off));
            float e = expf(v - mv);
            float ssum = e;
            for (int off = 32; off > 0; off >>= 1) ssum += __shfl_xor(ssum, off);
            float s = e / ssum;
            float n2 = s * s;
            for (int off = 32; off > 0; off >>= 1) n2 += __shfl_xor(n2, off);
            float uu = s * rsqrtf(n2);        // d_i >= 1/64 so max(.,1e-9) never binds
            emb[(size_t)(r0 + row) * DOUT + lane] = v;
            ut[(size_t)lane * NN + (r0 + row)] = uu;   // transposed scatter
        }
    }
}

// ---------------------------------------------------------------------------
// Column sums of u (= row sums of ut) in f64: one block per column c.
// ---------------------------------------------------------------------------
__global__ __launch_bounds__(256) void colsum_kernel(const float* __restrict__ ut,
                                                     double* __restrict__ colsum)
{
    __shared__ double cred[4];
    const int c = blockIdx.x, t = threadIdx.x;
    double a = 0.0;
    for (int i = t; i < NN; i += 256) a += (double)ut[(size_t)c * NN + i];
    for (int off = 32; off > 0; off >>= 1) a += __shfl_xor(a, off);
    if ((t & 63) == 0) cred[t >> 6] = a;
    __syncthreads();
    if (t == 0) colsum[c] = cred[0] + cred[1] + cred[2] + cred[3];
}

// ---------------------------------------------------------------------------
// max_{i!=j} u_i . u_j over 64x64 tiles (upper triangle). Tiles from ut:
// contiguous b128 staging (conflict-free).
// ---------------------------------------------------------------------------
__global__ __launch_bounds__(256) void max_kernel(const float* __restrict__ ut,
                                                  unsigned int* __restrict__ mx)
{
    const int ti = blockIdx.x, tj = blockIdx.y;
    if (tj < ti) return;
    __shared__ float uit[64 * 64];
    __shared__ float ujt[64 * 64];
    __shared__ float red[4];
    const int t = threadIdx.x;
    #pragma unroll
    for (int it = 0; it < 4; ++it) {
        const int p = t + it * 256;
        const int k = p >> 4, j4 = p & 15;
        *reinterpret_cast<float4*>(&uit[k * 64 + j4 * 4]) =
            *reinterpret_cast<const float4*>(&ut[(size_t)k * NN + ti * 64 + j4 * 4]);
        *reinterpret_cast<float4*>(&ujt[k * 64 + j4 * 4]) =
            *reinterpret_cast<const float4*>(&ut[(size_t)k * NN + tj * 64 + j4 * 4]);
    }
    __syncthreads();
    const int tx = t & 15, ty = t >> 4;
    float r16[16];
    #pragma unroll
    for (int s = 0; s < 16; ++s) r16[s] = 0.f;
    #pragma unroll 8
    for (int k = 0; k < 64; ++k) {
        float4 a4 = *reinterpret_cast<const float4*>(&uit[k * 64 + ty * 4]);
        float4 b4 = *reinterpret_cast<const float4*>(&ujt[k * 64 + tx * 4]);
        float av[4] = {a4.x, a4.y, a4.z, a4.w};
        float bv[4] = {b4.x, b4.y, b4.z, b4.w};
        #pragma unroll
        for (int aa = 0; aa < 4; ++aa)
            #pragma unroll
            for (int bb = 0; bb < 4; ++bb)
                r16[aa * 4 + bb] = fmaf(av[aa], bv[bb], r16[aa * 4 + bb]);
    }
    float lm = 0.f;
    #pragma unroll
    for (int aa = 0; aa < 4; ++aa)
        #pragma unroll
        for (int bb = 0; bb < 4; ++bb) {
            const int gi = ti * 64 + ty * 4 + aa;
            const int gj = tj * 64 + tx * 4 + bb;
            if (gi != gj) lm = fmaxf(lm, r16[aa * 4 + bb]);
        }
    for (int off = 32; off > 0; off >>= 1) lm = fmaxf(lm, __shfl_xor(lm, off));
    if ((t & 63) == 0) red[t >> 6] = lm;
    __syncthreads();
    if (t == 0) {
        float bm = fmaxf(fmaxf(red[0], red[1]), fmaxf(red[2], red[3]));
        atomicMax(mx, __float_as_uint(bm));
    }
}

__global__ void finalize_kernel(const double* __restrict__ colsum,
                                const unsigned int* __restrict__ mx,
                                float* __restrict__ scal)
{
    const int c = threadIdx.x;   // 64 threads = 1 wave
    double cs = colsum[c];
    double s2 = cs * cs;
    for (int off = 32; off > 0; off >>= 1) s2 += __shfl_xor(s2, off);
    if (c == 0) {
        double md = (s2 - (double)NN) / ((double)NN * (double)NN);
        float mf = (float)md;
        float mxv = __uint_as_float(mx[0]);
        scal[0] = mf;
        scal[1] = 1.0f / (mxv - mf);
        scal[2] = 1.0f / mf;
    }
}

// ---------------------------------------------------------------------------
// Fused propagation, LDS-minimized. 768 blocks x 8 rows. Per j-tile:
//   dot (2-way k-split, ui in regs, b128 ujt) -> transform -> vs (LDS)
//   -> acc: vs b128 broadcast + emb direct from global (L2-resident).
// Final: 16-way jsub reduction, fused softmax, f32 out.
// ---------------------------------------------------------------------------
__global__ __launch_bounds__(256, 3) void prop_fused_kernel(
    const float* __restrict__ ut, const float* __restrict__ emb,
    const float* __restrict__ scal, const float* __restrict__ ah_p,
    float* __restrict__ out3)
{
    __shared__ float ujt[64 * 64];   // [k][j] tile from ut, linear, 16 KB
    __shared__ float vs[8 * 68];     // [i][j] transformed (stride 68: 16B-aligned rows)
    __shared__ float pr[128 * 4];    // k-split partial r
    __shared__ float redp[8 * 64];
    __shared__ float redn[8 * 64];

    const int t = threadIdx.x;
    const int bi = blockIdx.x;       // rows bi*8 .. +7
    const float m = scal[0], inv_pd = scal[1], inv_m = scal[2];
    const float alpha = ah_p[0];

    const int ksub = t >> 7;         // 0,1 : k-half
    const int slot = t & 127;
    const int di = slot >> 4;        // 0..7 row
    const int jq = slot & 15;        // 0..15 j-group (4 j each)
    const int jsub = t >> 4;         // 0..15 acc j-group
    const int cq = t & 15;           // acc col-quarter

    // ui row (bi*8+di), k in [ksub*32, +32) from ut columns -> registers
    float uk[32];
    #pragma unroll 8
    for (int kk = 0; kk < 32; ++kk)
        uk[kk] = ut[(size_t)(ksub * 32 + kk) * NN + bi * 8 + di];

    float4 accp[8], accn[8];
    #pragma unroll
    for (int r = 0; r < 8; ++r) {
        accp[r].x = accp[r].y = accp[r].z = accp[r].w = 0.f;
        accn[r].x = accn[r].y = accn[r].z = accn[r].w = 0.f;
    }

    // stage j-tile 0
    #pragma unroll
    for (int it = 0; it < 4; ++it) {
        const int p = t + it * 256;
        const int k = p >> 4, j4 = p & 15;
        *reinterpret_cast<float4*>(&ujt[k * 64 + j4 * 4]) =
            *reinterpret_cast<const float4*>(&ut[(size_t)k * NN + 0 * 64 + j4 * 4]);
    }
    __syncthreads();

    for (int jt = 0; jt < 96; ++jt) {
        // ---- dot: r[4] over my 32 k ----
        float r0 = 0.f, r1 = 0.f, r2 = 0.f, r3 = 0.f;
        {
            const float* basep = &ujt[(ksub * 32) * 64 + jq * 4];
            #pragma unroll 8
            for (int kk = 0; kk < 32; ++kk) {
                float4 b = *reinterpret_cast<const float4*>(basep + kk * 64);
                r0 = fmaf(uk[kk], b.x, r0);
                r1 = fmaf(uk[kk], b.y, r1);
                r2 = fmaf(uk[kk], b.z, r2);
                r3 = fmaf(uk[kk], b.w, r3);
            }
        }
        if (ksub) {
            float4 v; v.x = r0; v.y = r1; v.z = r2; v.w = r3;
            *reinterpret_cast<float4*>(&pr[slot * 4]) = v;
        }
        __syncthreads();
        if (!ksub) {
            float4 o = *reinterpret_cast<const float4*>(&pr[slot * 4]);
            r0 += o.x; r1 += o.y; r2 += o.z; r3 += o.w;
            const int gi = bi * 8 + di;
            float rr[4] = {r0, r1, r2, r3};
            float4 vv;
            #pragma unroll
            for (int s = 0; s < 4; ++s) {
                const int gj = jt * 64 + jq * 4 + s;
                float lre = (gi == gj) ? 0.f : rr[s];
                float x = lre - m;
                float v = (x > 0.f) ? x * inv_pd : -(lre * inv_m);
                if (gi == gj) v += 1.f;     // add_diag after where
                (&vv.x)[s] = v;
            }
            *reinterpret_cast<float4*>(&vs[di * 68 + jq * 4]) = vv;
        }
        __syncthreads();

        // ---- acc (reads vs + emb-global) overlapped with staging jt+1 ----
        if (jt + 1 < 96) {
            #pragma unroll
            for (int it = 0; it < 4; ++it) {
                const int p = t + it * 256;
                const int k = p >> 4, j4 = p & 15;
                *reinterpret_cast<float4*>(&ujt[k * 64 + j4 * 4]) =
                    *reinterpret_cast<const float4*>(
                        &ut[(size_t)k * NN + (jt + 1) * 64 + j4 * 4]);
            }
        }
        float4 v4[8];
        #pragma unroll
        for (int r = 0; r < 8; ++r)
            v4[r] = *reinterpret_cast<const float4*>(&vs[r * 68 + jsub * 4]);
        #pragma unroll
        for (int q = 0; q < 4; ++q) {
            float4 e = *reinterpret_cast<const float4*>(
                &emb[((size_t)jt * 64 + jsub * 4 + q) * 64 + cq * 4]);
            #pragma unroll
            for (int r = 0; r < 8; ++r) {
                float v = (&v4[r].x)[q];
                float p  = (v >= 0.f) ? v : alpha * v;
                float nv = -v;
                float ng = (nv >= 0.f) ? nv : alpha * nv;
                accp[r].x = fmaf(p, e.x, accp[r].x);
                accp[r].y = fmaf(p, e.y, accp[r].y);
                accp[r].z = fmaf(p, e.z, accp[r].z);
                accp[r].w = fmaf(p, e.w, accp[r].w);
                accn[r].x = fmaf(ng, e.x, accn[r].x);
                accn[r].y = fmaf(ng, e.y, accn[r].y);
                accn[r].z = fmaf(ng, e.z, accn[r].z);
                accn[r].w = fmaf(ng, e.w, accn[r].w);
            }
        }
        __syncthreads();
    }

    // ---- 16-way reduction over jsub into redp/redn ----
    for (int g = 0; g < 16; ++g) {
        if (jsub == g) {
            #pragma unroll
            for (int r = 0; r < 8; ++r) {
                float4 pv = accp[r], nv = accn[r];
                if (g) {
                    float4 op = *reinterpret_cast<const float4*>(&redp[r * 64 + cq * 4]);
                    float4 on = *reinterpret_cast<const float4*>(&redn[r * 64 + cq * 4]);
                    pv.x += op.x; pv.y += op.y; pv.z += op.z; pv.w += op.w;
                    nv.x += on.x; nv.y += on.y; nv.z += on.z; nv.w += on.w;
                }
                *reinterpret_cast<float4*>(&redp[r * 64 + cq * 4]) = pv;
                *reinterpret_cast<float4*>(&redn[r * 64 + cq * 4]) = nv;
            }
        }
        __syncthreads();
    }

    // ---- fused softmax + epilogue: wave w handles rows w and w+4 ----
    {
        const int w = t >> 6, lane = t & 63;
        #pragma unroll
        for (int rep = 0; rep < 2; ++rep) {
            const int row = w + rep * 4;
            float zp = redp[row * 64 + lane];
            float mp = zp;
            for (int off = 32; off > 0; off >>= 1) mp = fmaxf(mp, __shfl_xor(mp, off));
            float ep = __expf(zp - mp);
            float sump = ep;
            for (int off = 32; off > 0; off >>= 1) sump += __shfl_xor(sump, off);
            float pp = ep / sump;

            float zn = redn[row * 64 + lane];
            float mn = zn;
            for (int off = 32; off > 0; off >>= 1) mn = fmaxf(mn, __shfl_xor(mn, off));
            float en = __expf(zn - mn);
            float sumn = en;
            for (int off = 32; off > 0; off >>= 1) sumn += __shfl_xor(sumn, off);
            float pn = en / sumn;

            const size_t gi = (size_t)bi * 8 + row;
            out3[gi * 64 + lane] = 0.5f * (pp - pn + emb[gi * 64 + lane]);
        }
    }
}

extern "C" void kernel_launch(void* const* d_in, const int* in_sizes, int n_in,
                              void* d_out, int out_size, void* d_ws, size_t ws_size,
                              hipStream_t stream)
{
    (void)in_sizes; (void)n_in; (void)out_size; (void)ws_size;
    const float* ori = (const float*)d_in[0];
    const float* sm  = (const float*)d_in[1];
    // d_in[2] processed_feature: unused; d_in[3] universal_re: unused (BETA=0)
    const float* W0s = (const float*)d_in[4];
    const float* b0s = (const float*)d_in[5];
    const float* W1s = (const float*)d_in[6];
    const float* b1s = (const float*)d_in[7];
    const float* W0l = (const float*)d_in[8];
    const float* b0l = (const float*)d_in[9];
    const float* W1l = (const float*)d_in[10];
    const float* b1l = (const float*)d_in[11];
    const float* W0h = (const float*)d_in[12];
    const float* b0h = (const float*)d_in[13];
    const float* W1h = (const float*)d_in[14];
    const float* b1h = (const float*)d_in[15];
    const float* amp = (const float*)d_in[16];
    const float* ahp = (const float*)d_in[17];

    float* out = (float*)d_out;                       // f32 output (ref dtype)
    float* ws = (float*)d_ws;
    float* emb = ws;                                  // NN*64 f32
    float* ut  = ws + (size_t)NN * DOUT;              // 64*NN f32 (u transposed)
    double* colsum = (double*)(ws + (size_t)2 * NN * DOUT);   // 64 f64
    unsigned int* mx = (unsigned int*)(ws + (size_t)2 * NN * DOUT + 256);
    float* scal = ws + (size_t)2 * NN * DOUT + 256 + 4;       // 3 f32
    // ws footprint ~3.15 MB (same as the passing round)

    hipMemsetAsync(mx, 0, 4, stream);
    mlp_kernel<<<dim3(NN / 8, 3), 256, 0, stream>>>(
        ori, sm, W0s, b0s, W1s, b1s, W0l, b0l, W1l, b1l,
        W0h, b0h, W1h, b1h, amp, ahp, out, emb, ut);
    colsum_kernel<<<64, 256, 0, stream>>>(ut, colsum);
    max_kernel<<<dim3(96, 96), 256, 0, stream>>>(ut, mx);
    finalize_kernel<<<1, 64, 0, stream>>>(colsum, mx, scal);
    prop_fused_kernel<<<NN / 8, 256, 0, stream>>>(ut, emb, scal, ahp,
                                                  out + (size_t)2 * NN * DOUT);
}

// Round 5
// 412.897 us; speedup vs baseline: 2.4860x; 2.4860x over previous
//
#include <hip/hip_runtime.h>
#include <hip/hip_bf16.h>

#define NN 6144
#define FEATN 128
#define INSM 512
#define HIDN 256
#define DOUT 64

// ---------------------------------------------------------------------------
// Branch MLPs: out = prelu(X@W0+b0, a) @ W1 + b1.   (outputs FLOAT32)
// blockIdx.y: 0 = local(ori)->out0, 1 = smooth->out1, 2 = hete->emb, ut (ws)
// br==2 writes u TRANSPOSED: ut[64][6144] (ut[c][i] = u[i][c]).
// ---------------------------------------------------------------------------
__global__ __launch_bounds__(256) void mlp_kernel(
    const float* __restrict__ ori, const float* __restrict__ sm,
    const float* __restrict__ W0s, const float* __restrict__ b0s,
    const float* __restrict__ W1s, const float* __restrict__ b1s,
    const float* __restrict__ W0l, const float* __restrict__ b0l,
    const float* __restrict__ W1l, const float* __restrict__ b1l,
    const float* __restrict__ W0h, const float* __restrict__ b0h,
    const float* __restrict__ W1h, const float* __restrict__ b1h,
    const float* __restrict__ am_p, const float* __restrict__ ah_p,
    float* __restrict__ out, float* __restrict__ emb, float* __restrict__ ut)
{
    __shared__ float xs[8 * INSM];
    __shared__ float hs[8 * HIDN];
    __shared__ float vals[8 * DOUT];
    const int t = threadIdx.x;
    const int br = blockIdx.y;
    const int r0 = blockIdx.x * 8;

    const float *X, *W0, *b0, *W1, *b1;
    int IN;
    float alpha;
    if (br == 0)      { X = ori; W0 = W0l; b0 = b0l; W1 = W1l; b1 = b1l; IN = FEATN; alpha = am_p[0]; }
    else if (br == 1) { X = sm;  W0 = W0s; b0 = b0s; W1 = W1s; b1 = b1s; IN = INSM;  alpha = am_p[0]; }
    else              { X = sm;  W0 = W0h; b0 = b0h; W1 = W1h; b1 = b1h; IN = INSM;  alpha = ah_p[0]; }

    const float* Xb = X + (size_t)r0 * IN;
    const int tot4 = (8 * IN) >> 2;
    for (int i = t; i < tot4; i += 256)
        reinterpret_cast<float4*>(xs)[i] = reinterpret_cast<const float4*>(Xb)[i];
    __syncthreads();

    float acc[8];
    #pragma unroll
    for (int r = 0; r < 8; ++r) acc[r] = 0.f;
    for (int k = 0; k < IN; k += 4) {
        const float w0 = W0[(k + 0) * HIDN + t];
        const float w1 = W0[(k + 1) * HIDN + t];
        const float w2 = W0[(k + 2) * HIDN + t];
        const float w3 = W0[(k + 3) * HIDN + t];
        #pragma unroll
        for (int r = 0; r < 8; ++r) {
            float4 x4 = *reinterpret_cast<const float4*>(&xs[r * IN + k]);
            acc[r] = fmaf(x4.x, w0, acc[r]);
            acc[r] = fmaf(x4.y, w1, acc[r]);
            acc[r] = fmaf(x4.z, w2, acc[r]);
            acc[r] = fmaf(x4.w, w3, acc[r]);
        }
    }
    {
        float bb = b0[t];
        #pragma unroll
        for (int r = 0; r < 8; ++r) {
            float h = acc[r] + bb;
            hs[r * HIDN + t] = (h >= 0.f) ? h : alpha * h;
        }
    }
    __syncthreads();

    for (int task = t; task < 512; task += 256) {
        const int r = task >> 6, c = task & 63;
        float a2 = b1[c];
        for (int k = 0; k < HIDN; k += 4) {
            float4 h4 = *reinterpret_cast<const float4*>(&hs[r * HIDN + k]);
            a2 = fmaf(h4.x, W1[(k + 0) * DOUT + c], a2);
            a2 = fmaf(h4.y, W1[(k + 1) * DOUT + c], a2);
            a2 = fmaf(h4.z, W1[(k + 2) * DOUT + c], a2);
            a2 = fmaf(h4.w, W1[(k + 3) * DOUT + c], a2);
        }
        if (br < 2) {
            float* dst = out + (size_t)br * NN * DOUT;
            dst[(size_t)(r0 + r) * DOUT + c] = a2;
        } else {
            vals[r * DOUT + c] = a2;
        }
    }
    if (br == 2) {
        __syncthreads();
        const int wv = t >> 6, lane = t & 63;
        #pragma unroll
        for (int rep = 0; rep < 2; ++rep) {
            const int row = wv * 2 + rep;
            float v = vals[row * DOUT + lane];
            float mv = v;
            for (int off = 32; off > 0; off >>= 1) mv = fmaxf(mv, __shfl_xor(mv, off));
            float e = expf(v - mv);
            float ssum = e;
            for (int off = 32; off > 0; off >>= 1) ssum += __shfl_xor(ssum, off);
            float s = e / ssum;
            float n2 = s * s;
            for (int off = 32; off > 0; off >>= 1) n2 += __shfl_xor(n2, off);
            float uu = s * rsqrtf(n2);        // d_i >= 1/64 so max(.,1e-9) never binds
            emb[(size_t)(r0 + row) * DOUT + lane] = v;
            ut[(size_t)lane * NN + (r0 + row)] = uu;   // transposed scatter
        }
    }
}

// ---------------------------------------------------------------------------
// Column sums of u (= row sums of ut) in f64: one block per column c.
// ---------------------------------------------------------------------------
__global__ __launch_bounds__(256) void colsum_kernel(const float* __restrict__ ut,
                                                     double* __restrict__ colsum)
{
    __shared__ double cred[4];
    const int c = blockIdx.x, t = threadIdx.x;
    double a = 0.0;
    for (int i = t; i < NN; i += 256) a += (double)ut[(size_t)c * NN + i];
    for (int off = 32; off > 0; off >>= 1) a += __shfl_xor(a, off);
    if ((t & 63) == 0) cred[t >> 6] = a;
    __syncthreads();
    if (t == 0) colsum[c] = cred[0] + cred[1] + cred[2] + cred[3];
}

// ---------------------------------------------------------------------------
// R = u u^T tile GEMM, optionally storing R and/or accumulating max(off-diag).
// sym=1: triangular grid (tj >= tig), stores both the tile and its transpose.
// sym=0: rectangular strip rows [row0, row0+gridDim.x*64) x all j.
// Staging/dot identical to the round-3/4 max_kernel (proven 0-conflict).
// ---------------------------------------------------------------------------
__global__ __launch_bounds__(256) void r_gemm_kernel(
    const float* __restrict__ ut, float* __restrict__ R,
    unsigned int* __restrict__ mx,
    int row0, int sym, int do_store, int do_max)
{
    const int tix = blockIdx.x;            // strip-local i tile
    const int tj  = blockIdx.y;            // global j tile
    const int tig = (row0 >> 6) + tix;     // global i tile
    if (sym && tj < tig) return;
    __shared__ float uit[64 * 64];
    __shared__ float ujt[64 * 64];
    __shared__ float red[4];
    const int t = threadIdx.x;
    #pragma unroll
    for (int it = 0; it < 4; ++it) {
        const int p = t + it * 256;
        const int k = p >> 4, j4 = p & 15;
        *reinterpret_cast<float4*>(&uit[k * 64 + j4 * 4]) =
            *reinterpret_cast<const float4*>(&ut[(size_t)k * NN + tig * 64 + j4 * 4]);
        *reinterpret_cast<float4*>(&ujt[k * 64 + j4 * 4]) =
            *reinterpret_cast<const float4*>(&ut[(size_t)k * NN + tj * 64 + j4 * 4]);
    }
    __syncthreads();
    const int tx = t & 15, ty = t >> 4;
    float r16[16];
    #pragma unroll
    for (int s = 0; s < 16; ++s) r16[s] = 0.f;
    #pragma unroll 8
    for (int k = 0; k < 64; ++k) {
        float4 a4 = *reinterpret_cast<const float4*>(&uit[k * 64 + ty * 4]);
        float4 b4 = *reinterpret_cast<const float4*>(&ujt[k * 64 + tx * 4]);
        float av[4] = {a4.x, a4.y, a4.z, a4.w};
        float bv[4] = {b4.x, b4.y, b4.z, b4.w};
        #pragma unroll
        for (int aa = 0; aa < 4; ++aa)
            #pragma unroll
            for (int bb = 0; bb < 4; ++bb)
                r16[aa * 4 + bb] = fmaf(av[aa], bv[bb], r16[aa * 4 + bb]);
    }
    if (do_store) {
        #pragma unroll
        for (int aa = 0; aa < 4; ++aa) {
            float4 vv;
            vv.x = r16[aa * 4 + 0]; vv.y = r16[aa * 4 + 1];
            vv.z = r16[aa * 4 + 2]; vv.w = r16[aa * 4 + 3];
            *reinterpret_cast<float4*>(
                &R[(size_t)(tix * 64 + ty * 4 + aa) * NN + tj * 64 + tx * 4]) = vv;
        }
        if (sym && tj != tig) {   // mirrored tile (strip-local == global when sym)
            #pragma unroll
            for (int bb = 0; bb < 4; ++bb) {
                float4 vv;
                vv.x = r16[0 * 4 + bb]; vv.y = r16[1 * 4 + bb];
                vv.z = r16[2 * 4 + bb]; vv.w = r16[3 * 4 + bb];
                *reinterpret_cast<float4*>(
                    &R[(size_t)(tj * 64 + tx * 4 + bb) * NN + tig * 64 + ty * 4]) = vv;
            }
        }
    }
    if (do_max) {
        float lm = 0.f;
        #pragma unroll
        for (int aa = 0; aa < 4; ++aa)
            #pragma unroll
            for (int bb = 0; bb < 4; ++bb) {
                const int gi = tig * 64 + ty * 4 + aa;
                const int gj = tj * 64 + tx * 4 + bb;
                if (gi != gj) lm = fmaxf(lm, r16[aa * 4 + bb]);
            }
        for (int off = 32; off > 0; off >>= 1) lm = fmaxf(lm, __shfl_xor(lm, off));
        if ((t & 63) == 0) red[t >> 6] = lm;
        __syncthreads();
        if (t == 0) {
            float bm = fmaxf(fmaxf(red[0], red[1]), fmaxf(red[2], red[3]));
            atomicMax(mx, __float_as_uint(bm));   // all candidates > 0
        }
    }
}

__global__ void finalize_kernel(const double* __restrict__ colsum,
                                const unsigned int* __restrict__ mx,
                                float* __restrict__ scal)
{
    const int c = threadIdx.x;   // 64 threads = 1 wave
    double cs = colsum[c];
    double s2 = cs * cs;
    for (int off = 32; off > 0; off >>= 1) s2 += __shfl_xor(s2, off);
    if (c == 0) {
        double md = (s2 - (double)NN) / ((double)NN * (double)NN);
        float mf = (float)md;
        float mxv = __uint_as_float(mx[0]);
        scal[0] = mf;
        scal[1] = 1.0f / (mxv - mf);
        scal[2] = 1.0f / mf;
    }
}

// ---------------------------------------------------------------------------
// Propagation from stored R. One block = 8 output rows (strip-local), sweep
// 96 j-tiles: load R rows (global b128, VMEM pipe), transform -> vs (LDS),
// acc 4x4x(p,n) into 32 scalar regs (no spill). Fused softmax epilogue.
// ---------------------------------------------------------------------------
__global__ __launch_bounds__(256) void prop2_kernel(
    const float* __restrict__ R, const float* __restrict__ emb,
    const float* __restrict__ scal, const float* __restrict__ ah_p,
    float* __restrict__ out3, int row0)
{
    __shared__ float embl[64 * 68];   // [j][c] tile of emb
    __shared__ float vs[8 * 68];      // [i][j] transformed
    __shared__ float redp[8 * 64];
    __shared__ float redn[8 * 64];

    const int t = threadIdx.x;
    const int bi = blockIdx.x;        // strip-local, rows bi*8..+7
    const float m = scal[0], inv_pd = scal[1], inv_m = scal[2];
    const float alpha = ah_p[0];

    const int iq2 = t >> 7;           // 0..1 -> rows iq2*4+si
    const int jp  = (t >> 4) & 7;     // 0..7 j-phase
    const int cq  = t & 15;           // col quarter

    float accp[16], accn[16];
    #pragma unroll
    for (int s = 0; s < 16; ++s) { accp[s] = 0.f; accn[s] = 0.f; }

    for (int jt = 0; jt < 96; ++jt) {
        // stage emb tile (linear b128, conflict-free)
        #pragma unroll
        for (int it = 0; it < 4; ++it) {
            const int p = t + it * 256;
            const int j = p >> 4, c4 = p & 15;
            *reinterpret_cast<float4*>(&embl[j * 68 + c4 * 4]) =
                *reinterpret_cast<const float4*>(&emb[((size_t)jt * 64 + j) * 64 + c4 * 4]);
        }
        // load + transform R rows -> vs
        if (t < 128) {
            const int di = t >> 4, jq = t & 15;
            float4 r4 = *reinterpret_cast<const float4*>(
                &R[(size_t)(bi * 8 + di) * NN + jt * 64 + jq * 4]);
            const int gi = row0 + bi * 8 + di;
            float rr[4] = {r4.x, r4.y, r4.z, r4.w};
            float4 vv;
            #pragma unroll
            for (int s = 0; s < 4; ++s) {
                const int gj = jt * 64 + jq * 4 + s;
                float lre = (gi == gj) ? 0.f : rr[s];
                float x = lre - m;
                float v = (x > 0.f) ? x * inv_pd : -(lre * inv_m);
                if (gi == gj) v += 1.f;   // add_diag after where
                (&vv.x)[s] = v;
            }
            *reinterpret_cast<float4*>(&vs[di * 68 + jq * 4]) = vv;
        }
        __syncthreads();

        #pragma unroll
        for (int n = 0; n < 8; ++n) {
            const int jj = jp + 8 * n;
            float4 e = *reinterpret_cast<const float4*>(&embl[jj * 68 + cq * 4]);
            #pragma unroll
            for (int si = 0; si < 4; ++si) {
                float v = vs[(iq2 * 4 + si) * 68 + jj];
                float mx_ = fmaxf(v, 0.f), mn_ = fminf(v, 0.f);
                float p_ = fmaf(alpha, mn_, mx_);      // prelu(v)
                float ng = -fmaf(alpha, mx_, mn_);     // prelu(-v)
                accp[si * 4 + 0] = fmaf(p_, e.x, accp[si * 4 + 0]);
                accp[si * 4 + 1] = fmaf(p_, e.y, accp[si * 4 + 1]);
                accp[si * 4 + 2] = fmaf(p_, e.z, accp[si * 4 + 2]);
                accp[si * 4 + 3] = fmaf(p_, e.w, accp[si * 4 + 3]);
                accn[si * 4 + 0] = fmaf(ng, e.x, accn[si * 4 + 0]);
                accn[si * 4 + 1] = fmaf(ng, e.y, accn[si * 4 + 1]);
                accn[si * 4 + 2] = fmaf(ng, e.z, accn[si * 4 + 2]);
                accn[si * 4 + 3] = fmaf(ng, e.w, accn[si * 4 + 3]);
            }
        }
        __syncthreads();
    }

    // reduce over the 8 j-phases
    for (int g = 0; g < 8; ++g) {
        if (jp == g) {
            #pragma unroll
            for (int si = 0; si < 4; ++si) {
                const int idx = (iq2 * 4 + si) * 64 + cq * 4;
                float4 pv, nv;
                pv.x = accp[si*4+0]; pv.y = accp[si*4+1]; pv.z = accp[si*4+2]; pv.w = accp[si*4+3];
                nv.x = accn[si*4+0]; nv.y = accn[si*4+1]; nv.z = accn[si*4+2]; nv.w = accn[si*4+3];
                if (g) {
                    float4 op = *reinterpret_cast<const float4*>(&redp[idx]);
                    float4 on = *reinterpret_cast<const float4*>(&redn[idx]);
                    pv.x += op.x; pv.y += op.y; pv.z += op.z; pv.w += op.w;
                    nv.x += on.x; nv.y += on.y; nv.z += on.z; nv.w += on.w;
                }
                *reinterpret_cast<float4*>(&redp[idx]) = pv;
                *reinterpret_cast<float4*>(&redn[idx]) = nv;
            }
        }
        __syncthreads();
    }

    // fused softmax + epilogue: wave w handles rows w and w+4
    {
        const int w = t >> 6, lane = t & 63;
        #pragma unroll
        for (int rep = 0; rep < 2; ++rep) {
            const int row = w + rep * 4;
            float zp = redp[row * 64 + lane];
            float mp = zp;
            for (int off = 32; off > 0; off >>= 1) mp = fmaxf(mp, __shfl_xor(mp, off));
            float ep = __expf(zp - mp);
            float sump = ep;
            for (int off = 32; off > 0; off >>= 1) sump += __shfl_xor(sump, off);
            float pp = ep / sump;

            float zn = redn[row * 64 + lane];
            float mn = zn;
            for (int off = 32; off > 0; off >>= 1) mn = fmaxf(mn, __shfl_xor(mn, off));
            float en = __expf(zn - mn);
            float sumn = en;
            for (int off = 32; off > 0; off >>= 1) sumn += __shfl_xor(sumn, off);
            float pn = en / sumn;

            const size_t gi = (size_t)row0 + bi * 8 + row;
            out3[gi * 64 + lane] = 0.5f * (pp - pn + emb[gi * 64 + lane]);
        }
    }
}

extern "C" void kernel_launch(void* const* d_in, const int* in_sizes, int n_in,
                              void* d_out, int out_size, void* d_ws, size_t ws_size,
                              hipStream_t stream)
{
    (void)in_sizes; (void)n_in; (void)out_size;
    const float* ori = (const float*)d_in[0];
    const float* sm  = (const float*)d_in[1];
    // d_in[2] processed_feature: unused; d_in[3] universal_re: unused (BETA=0)
    const float* W0s = (const float*)d_in[4];
    const float* b0s = (const float*)d_in[5];
    const float* W1s = (const float*)d_in[6];
    const float* b1s = (const float*)d_in[7];
    const float* W0l = (const float*)d_in[8];
    const float* b0l = (const float*)d_in[9];
    const float* W1l = (const float*)d_in[10];
    const float* b1l = (const float*)d_in[11];
    const float* W0h = (const float*)d_in[12];
    const float* b0h = (const float*)d_in[13];
    const float* W1h = (const float*)d_in[14];
    const float* b1h = (const float*)d_in[15];
    const float* amp = (const float*)d_in[16];
    const float* ahp = (const float*)d_in[17];

    float* out = (float*)d_out;                       // f32 output (ref dtype)
    float* ws = (float*)d_ws;
    float* emb = ws;                                  // NN*64 f32
    float* ut  = ws + (size_t)NN * DOUT;              // 64*NN f32 (u transposed)
    double* colsum = (double*)(ws + (size_t)2 * NN * DOUT);   // 64 f64 (=128 f32)
    unsigned int* mx = (unsigned int*)(ws + (size_t)2 * NN * DOUT + 128);
    float* scal = ws + (size_t)2 * NN * DOUT + 128 + 4;       // 3 f32
    size_t R_off = (((size_t)2 * NN * DOUT + 128 + 8) + 15) & ~(size_t)15;
    float* R = ws + R_off;

    // How many R rows fit in the remaining workspace?
    size_t ws_f = ws_size / 4;
    size_t avail = (ws_f > R_off) ? (ws_f - R_off) : 0;
    int sr = (int)((avail / NN) / 64) * 64;           // rows per strip, x64
    if (sr < 64) sr = 64;                              // minimal strip (1.5 MB)
    if (sr > NN) sr = NN;
    const int nstrips = (NN + sr - 1) / sr;

    hipMemsetAsync(mx, 0, 4, stream);
    mlp_kernel<<<dim3(NN / 8, 3), 256, 0, stream>>>(
        ori, sm, W0s, b0s, W1s, b1s, W0l, b0l, W1l, b1l,
        W0h, b0h, W1h, b1h, amp, ahp, out, emb, ut);
    colsum_kernel<<<64, 256, 0, stream>>>(ut, colsum);

    float* out3 = out + (size_t)2 * NN * DOUT;
    if (nstrips == 1) {
        // single pass: triangular R GEMM with store + max, then consume
        r_gemm_kernel<<<dim3(96, 96), 256, 0, stream>>>(ut, R, mx, 0, 1, 1, 1);
        finalize_kernel<<<1, 64, 0, stream>>>(colsum, mx, scal);
        prop2_kernel<<<NN / 8, 256, 0, stream>>>(R, emb, scal, ahp, out3, 0);
    } else {
        // pass 1: max only (triangle, no store). Then per strip: rect
        // recompute+store followed immediately by consumption.
        r_gemm_kernel<<<dim3(96, 96), 256, 0, stream>>>(ut, R, mx, 0, 1, 0, 1);
        finalize_kernel<<<1, 64, 0, stream>>>(colsum, mx, scal);
        for (int s = 0; s < nstrips; ++s) {
            const int row0 = s * sr;
            const int rows = (NN - row0 < sr) ? (NN - row0) : sr;
            r_gemm_kernel<<<dim3(rows / 64, 96), 256, 0, stream>>>(
                ut, R, mx, row0, 0, 1, 0);
            prop2_kernel<<<rows / 8, 256, 0, stream>>>(
                R, emb, scal, ahp, out3, row0);
        }
    }
}

// Round 6
// 409.534 us; speedup vs baseline: 2.5064x; 1.0082x over previous
//
#include <hip/hip_runtime.h>
#include <hip/hip_bf16.h>

#define NN 6144
#define FEATN 128
#define INSM 512
#define HIDN 256
#define DOUT 64

// ---------------------------------------------------------------------------
// Branch MLPs: out = prelu(X@W0+b0, a) @ W1 + b1.   (outputs FLOAT32)
// blockIdx.y: 0 = local(ori)->out0, 1 = smooth->out1, 2 = hete->emb, ut (ws)
// br==2 writes u TRANSPOSED: ut[64][6144] (ut[c][i] = u[i][c]).
// ---------------------------------------------------------------------------
__global__ __launch_bounds__(256) void mlp_kernel(
    const float* __restrict__ ori, const float* __restrict__ sm,
    const float* __restrict__ W0s, const float* __restrict__ b0s,
    const float* __restrict__ W1s, const float* __restrict__ b1s,
    const float* __restrict__ W0l, const float* __restrict__ b0l,
    const float* __restrict__ W1l, const float* __restrict__ b1l,
    const float* __restrict__ W0h, const float* __restrict__ b0h,
    const float* __restrict__ W1h, const float* __restrict__ b1h,
    const float* __restrict__ am_p, const float* __restrict__ ah_p,
    float* __restrict__ out, float* __restrict__ emb, float* __restrict__ ut)
{
    __shared__ float xs[8 * INSM];
    __shared__ float hs[8 * HIDN];
    __shared__ float vals[8 * DOUT];
    const int t = threadIdx.x;
    const int br = blockIdx.y;
    const int r0 = blockIdx.x * 8;

    const float *X, *W0, *b0, *W1, *b1;
    int IN;
    float alpha;
    if (br == 0)      { X = ori; W0 = W0l; b0 = b0l; W1 = W1l; b1 = b1l; IN = FEATN; alpha = am_p[0]; }
    else if (br == 1) { X = sm;  W0 = W0s; b0 = b0s; W1 = W1s; b1 = b1s; IN = INSM;  alpha = am_p[0]; }
    else              { X = sm;  W0 = W0h; b0 = b0h; W1 = W1h; b1 = b1h; IN = INSM;  alpha = ah_p[0]; }

    const float* Xb = X + (size_t)r0 * IN;
    const int tot4 = (8 * IN) >> 2;
    for (int i = t; i < tot4; i += 256)
        reinterpret_cast<float4*>(xs)[i] = reinterpret_cast<const float4*>(Xb)[i];
    __syncthreads();

    float acc[8];
    #pragma unroll
    for (int r = 0; r < 8; ++r) acc[r] = 0.f;
    for (int k = 0; k < IN; k += 4) {
        const float w0 = W0[(k + 0) * HIDN + t];
        const float w1 = W0[(k + 1) * HIDN + t];
        const float w2 = W0[(k + 2) * HIDN + t];
        const float w3 = W0[(k + 3) * HIDN + t];
        #pragma unroll
        for (int r = 0; r < 8; ++r) {
            float4 x4 = *reinterpret_cast<const float4*>(&xs[r * IN + k]);
            acc[r] = fmaf(x4.x, w0, acc[r]);
            acc[r] = fmaf(x4.y, w1, acc[r]);
            acc[r] = fmaf(x4.z, w2, acc[r]);
            acc[r] = fmaf(x4.w, w3, acc[r]);
        }
    }
    {
        float bb = b0[t];
        #pragma unroll
        for (int r = 0; r < 8; ++r) {
            float h = acc[r] + bb;
            hs[r * HIDN + t] = (h >= 0.f) ? h : alpha * h;
        }
    }
    __syncthreads();

    for (int task = t; task < 512; task += 256) {
        const int r = task >> 6, c = task & 63;
        float a2 = b1[c];
        for (int k = 0; k < HIDN; k += 4) {
            float4 h4 = *reinterpret_cast<const float4*>(&hs[r * HIDN + k]);
            a2 = fmaf(h4.x, W1[(k + 0) * DOUT + c], a2);
            a2 = fmaf(h4.y, W1[(k + 1) * DOUT + c], a2);
            a2 = fmaf(h4.z, W1[(k + 2) * DOUT + c], a2);
            a2 = fmaf(h4.w, W1[(k + 3) * DOUT + c], a2);
        }
        if (br < 2) {
            float* dst = out + (size_t)br * NN * DOUT;
            dst[(size_t)(r0 + r) * DOUT + c] = a2;
        } else {
            vals[r * DOUT + c] = a2;
        }
    }
    if (br == 2) {
        __syncthreads();
        const int wv = t >> 6, lane = t & 63;
        #pragma unroll
        for (int rep = 0; rep < 2; ++rep) {
            const int row = wv * 2 + rep;
            float v = vals[row * DOUT + lane];
            float mv = v;
            for (int off = 32; off > 0; off >>= 1) mv = fmaxf(mv, __shfl_xor(mv, off));
            float e = expf(v - mv);
            float ssum = e;
            for (int off = 32; off > 0; off >>= 1) ssum += __shfl_xor(ssum, off);
            float s = e / ssum;
            float n2 = s * s;
            for (int off = 32; off > 0; off >>= 1) n2 += __shfl_xor(n2, off);
            float uu = s * rsqrtf(n2);        // d_i >= 1/64 so max(.,1e-9) never binds
            emb[(size_t)(r0 + row) * DOUT + lane] = v;
            ut[(size_t)lane * NN + (r0 + row)] = uu;   // transposed scatter
        }
    }
}

// ---------------------------------------------------------------------------
// Column sums of u (= row sums of ut) in f64: one block per column c.
// ---------------------------------------------------------------------------
__global__ __launch_bounds__(256) void colsum_kernel(const float* __restrict__ ut,
                                                     double* __restrict__ colsum)
{
    __shared__ double cred[4];
    const int c = blockIdx.x, t = threadIdx.x;
    double a = 0.0;
    for (int i = t; i < NN; i += 256) a += (double)ut[(size_t)c * NN + i];
    for (int off = 32; off > 0; off >>= 1) a += __shfl_xor(a, off);
    if ((t & 63) == 0) cred[t >> 6] = a;
    __syncthreads();
    if (t == 0) colsum[c] = cred[0] + cred[1] + cred[2] + cred[3];
}

// ---------------------------------------------------------------------------
// R = u u^T tile GEMM, optionally storing R and/or accumulating max(off-diag).
// sym=1: triangular grid (tj >= tig), stores both the tile and its transpose.
// sym=0: rectangular strip rows [row0, row0+gridDim.x*64) x all j.
// ---------------------------------------------------------------------------
__global__ __launch_bounds__(256) void r_gemm_kernel(
    const float* __restrict__ ut, float* __restrict__ R,
    unsigned int* __restrict__ mx,
    int row0, int sym, int do_store, int do_max)
{
    const int tix = blockIdx.x;            // strip-local i tile
    const int tj  = blockIdx.y;            // global j tile
    const int tig = (row0 >> 6) + tix;     // global i tile
    if (sym && tj < tig) return;
    __shared__ float uit[64 * 64];
    __shared__ float ujt[64 * 64];
    __shared__ float red[4];
    const int t = threadIdx.x;
    #pragma unroll
    for (int it = 0; it < 4; ++it) {
        const int p = t + it * 256;
        const int k = p >> 4, j4 = p & 15;
        *reinterpret_cast<float4*>(&uit[k * 64 + j4 * 4]) =
            *reinterpret_cast<const float4*>(&ut[(size_t)k * NN + tig * 64 + j4 * 4]);
        *reinterpret_cast<float4*>(&ujt[k * 64 + j4 * 4]) =
            *reinterpret_cast<const float4*>(&ut[(size_t)k * NN + tj * 64 + j4 * 4]);
    }
    __syncthreads();
    const int tx = t & 15, ty = t >> 4;
    float r16[16];
    #pragma unroll
    for (int s = 0; s < 16; ++s) r16[s] = 0.f;
    #pragma unroll 8
    for (int k = 0; k < 64; ++k) {
        float4 a4 = *reinterpret_cast<const float4*>(&uit[k * 64 + ty * 4]);
        float4 b4 = *reinterpret_cast<const float4*>(&ujt[k * 64 + tx * 4]);
        float av[4] = {a4.x, a4.y, a4.z, a4.w};
        float bv[4] = {b4.x, b4.y, b4.z, b4.w};
        #pragma unroll
        for (int aa = 0; aa < 4; ++aa)
            #pragma unroll
            for (int bb = 0; bb < 4; ++bb)
                r16[aa * 4 + bb] = fmaf(av[aa], bv[bb], r16[aa * 4 + bb]);
    }
    if (do_store) {
        #pragma unroll
        for (int aa = 0; aa < 4; ++aa) {
            float4 vv;
            vv.x = r16[aa * 4 + 0]; vv.y = r16[aa * 4 + 1];
            vv.z = r16[aa * 4 + 2]; vv.w = r16[aa * 4 + 3];
            *reinterpret_cast<float4*>(
                &R[(size_t)(tix * 64 + ty * 4 + aa) * NN + tj * 64 + tx * 4]) = vv;
        }
        if (sym && tj != tig) {   // mirrored tile (strip-local == global when sym)
            #pragma unroll
            for (int bb = 0; bb < 4; ++bb) {
                float4 vv;
                vv.x = r16[0 * 4 + bb]; vv.y = r16[1 * 4 + bb];
                vv.z = r16[2 * 4 + bb]; vv.w = r16[3 * 4 + bb];
                *reinterpret_cast<float4*>(
                    &R[(size_t)(tj * 64 + tx * 4 + bb) * NN + tig * 64 + ty * 4]) = vv;
            }
        }
    }
    if (do_max) {
        float lm = 0.f;
        #pragma unroll
        for (int aa = 0; aa < 4; ++aa)
            #pragma unroll
            for (int bb = 0; bb < 4; ++bb) {
                const int gi = tig * 64 + ty * 4 + aa;
                const int gj = tj * 64 + tx * 4 + bb;
                if (gi != gj) lm = fmaxf(lm, r16[aa * 4 + bb]);
            }
        for (int off = 32; off > 0; off >>= 1) lm = fmaxf(lm, __shfl_xor(lm, off));
        if ((t & 63) == 0) red[t >> 6] = lm;
        __syncthreads();
        if (t == 0) {
            float bm = fmaxf(fmaxf(red[0], red[1]), fmaxf(red[2], red[3]));
            atomicMax(mx, __float_as_uint(bm));   // all candidates > 0
        }
    }
}

__global__ void finalize_kernel(const double* __restrict__ colsum,
                                const unsigned int* __restrict__ mx,
                                float* __restrict__ scal)
{
    const int c = threadIdx.x;   // 64 threads = 1 wave
    double cs = colsum[c];
    double s2 = cs * cs;
    for (int off = 32; off > 0; off >>= 1) s2 += __shfl_xor(s2, off);
    if (c == 0) {
        double md = (s2 - (double)NN) / ((double)NN * (double)NN);
        float mf = (float)md;
        float mxv = __uint_as_float(mx[0]);
        scal[0] = mf;
        scal[1] = 1.0f / (mxv - mf);
        scal[2] = 1.0f / mf;
    }
}

// ---------------------------------------------------------------------------
// Propagation v2: 8 rows/block, j-step 128 (48 iterations).
//   transform: all 256 threads, 1 R-quad each (global b128) -> vs (LDS).
//   acc: thread (iq2,jp,cq) owns jj = jp*16..+15 CONTIGUOUS -> b128 vs reads.
//   embl stored with c-quad XOR-swizzled by (j>>4)&3 (unpadded 64-f rows) to
//   kill the 4-way jp-group bank alias (16*stride % 32 == 0 for any even
//   stride -- padding cannot fix it, swizzle can).
// ---------------------------------------------------------------------------
__global__ __launch_bounds__(256) void prop2_kernel(
    const float* __restrict__ R, const float* __restrict__ emb,
    const float* __restrict__ scal, const float* __restrict__ ah_p,
    float* __restrict__ out3, int row0)
{
    __shared__ float embl[128 * 64];  // [j][c] swizzled, 32 KB
    __shared__ float vs[8 * 136];     // [i][jj], pad 136
    __shared__ float redp[8 * 64];
    __shared__ float redn[8 * 64];

    const int t = threadIdx.x;
    const int bi = blockIdx.x;        // strip-local, rows bi*8..+7
    const float m = scal[0], inv_pd = scal[1], inv_m = scal[2];
    const float alpha = ah_p[0];

    const int iq2 = t >> 7;           // 0..1 -> rows iq2*4+si
    const int jp  = (t >> 4) & 7;     // 0..7 -> jj = jp*16..+15
    const int cq  = t & 15;           // col quarter

    const int tdi = t >> 5;           // transform: row 0..7
    const int tjq = t & 31;           // transform: j-quad 0..31

    float accp[16], accn[16];
    #pragma unroll
    for (int s = 0; s < 16; ++s) { accp[s] = 0.f; accn[s] = 0.f; }

    for (int jt = 0; jt < 48; ++jt) {
        // ---- stage emb 128x64 tile, c-quad swizzled by (j>>4)&3 ----
        #pragma unroll
        for (int it = 0; it < 8; ++it) {
            const int p = t + it * 256;
            const int j = p >> 4, c4 = p & 15;
            const int cs_ = (c4 ^ ((j >> 4) & 3)) * 4;
            *reinterpret_cast<float4*>(&embl[j * 64 + cs_]) =
                *reinterpret_cast<const float4*>(
                    &emb[((size_t)jt * 128 + j) * 64 + c4 * 4]);
        }
        // ---- load + transform R quad -> vs ----
        {
            float4 r4 = *reinterpret_cast<const float4*>(
                &R[(size_t)(bi * 8 + tdi) * NN + jt * 128 + tjq * 4]);
            const int gi = row0 + bi * 8 + tdi;
            float rr[4] = {r4.x, r4.y, r4.z, r4.w};
            float4 vv;
            #pragma unroll
            for (int s = 0; s < 4; ++s) {
                const int gj = jt * 128 + tjq * 4 + s;
                float lre = (gi == gj) ? 0.f : rr[s];
                float x = lre - m;
                float v = (x > 0.f) ? x * inv_pd : -(lre * inv_m);
                if (gi == gj) v += 1.f;   // add_diag after where
                (&vv.x)[s] = v;
            }
            *reinterpret_cast<float4*>(&vs[tdi * 136 + tjq * 4]) = vv;
        }
        __syncthreads();

        // ---- acc: 4 si-rows x 16 contiguous jj x 4 c x (p,n) ----
        #pragma unroll
        for (int si = 0; si < 4; ++si) {
            const int row = iq2 * 4 + si;
            #pragma unroll
            for (int q = 0; q < 4; ++q) {
                float4 v4 = *reinterpret_cast<const float4*>(
                    &vs[row * 136 + jp * 16 + q * 4]);
                #pragma unroll
                for (int s = 0; s < 4; ++s) {
                    const int jj = jp * 16 + q * 4 + s;
                    float v = (&v4.x)[s];
                    float mx_ = fmaxf(v, 0.f), mn_ = fminf(v, 0.f);
                    float p_ = fmaf(alpha, mn_, mx_);      // prelu(v)
                    float ng = -fmaf(alpha, mx_, mn_);     // prelu(-v)
                    float4 e = *reinterpret_cast<const float4*>(
                        &embl[jj * 64 + (cq ^ ((jj >> 4) & 3)) * 4]);
                    accp[si * 4 + 0] = fmaf(p_, e.x, accp[si * 4 + 0]);
                    accp[si * 4 + 1] = fmaf(p_, e.y, accp[si * 4 + 1]);
                    accp[si * 4 + 2] = fmaf(p_, e.z, accp[si * 4 + 2]);
                    accp[si * 4 + 3] = fmaf(p_, e.w, accp[si * 4 + 3]);
                    accn[si * 4 + 0] = fmaf(ng, e.x, accn[si * 4 + 0]);
                    accn[si * 4 + 1] = fmaf(ng, e.y, accn[si * 4 + 1]);
                    accn[si * 4 + 2] = fmaf(ng, e.z, accn[si * 4 + 2]);
                    accn[si * 4 + 3] = fmaf(ng, e.w, accn[si * 4 + 3]);
                }
            }
        }
        __syncthreads();
    }

    // ---- reduce over the 8 jp phases ----
    for (int g = 0; g < 8; ++g) {
        if (jp == g) {
            #pragma unroll
            for (int si = 0; si < 4; ++si) {
                const int idx = (iq2 * 4 + si) * 64 + cq * 4;
                float4 pv, nv;
                pv.x = accp[si*4+0]; pv.y = accp[si*4+1]; pv.z = accp[si*4+2]; pv.w = accp[si*4+3];
                nv.x = accn[si*4+0]; nv.y = accn[si*4+1]; nv.z = accn[si*4+2]; nv.w = accn[si*4+3];
                if (g) {
                    float4 op = *reinterpret_cast<const float4*>(&redp[idx]);
                    float4 on = *reinterpret_cast<const float4*>(&redn[idx]);
                    pv.x += op.x; pv.y += op.y; pv.z += op.z; pv.w += op.w;
                    nv.x += on.x; nv.y += on.y; nv.z += on.z; nv.w += on.w;
                }
                *reinterpret_cast<float4*>(&redp[idx]) = pv;
                *reinterpret_cast<float4*>(&redn[idx]) = nv;
            }
        }
        __syncthreads();
    }

    // ---- fused softmax + epilogue: wave w handles rows w and w+4 ----
    {
        const int w = t >> 6, lane = t & 63;
        #pragma unroll
        for (int rep = 0; rep < 2; ++rep) {
            const int row = w + rep * 4;
            float zp = redp[row * 64 + lane];
            float mp = zp;
            for (int off = 32; off > 0; off >>= 1) mp = fmaxf(mp, __shfl_xor(mp, off));
            float ep = __expf(zp - mp);
            float sump = ep;
            for (int off = 32; off > 0; off >>= 1) sump += __shfl_xor(sump, off);
            float pp = ep / sump;

            float zn = redn[row * 64 + lane];
            float mn = zn;
            for (int off = 32; off > 0; off >>= 1) mn = fmaxf(mn, __shfl_xor(mn, off));
            float en = __expf(zn - mn);
            float sumn = en;
            for (int off = 32; off > 0; off >>= 1) sumn += __shfl_xor(sumn, off);
            float pn = en / sumn;

            const size_t gi = (size_t)row0 + bi * 8 + row;
            out3[gi * 64 + lane] = 0.5f * (pp - pn + emb[gi * 64 + lane]);
        }
    }
}

extern "C" void kernel_launch(void* const* d_in, const int* in_sizes, int n_in,
                              void* d_out, int out_size, void* d_ws, size_t ws_size,
                              hipStream_t stream)
{
    (void)in_sizes; (void)n_in; (void)out_size;
    const float* ori = (const float*)d_in[0];
    const float* sm  = (const float*)d_in[1];
    // d_in[2] processed_feature: unused; d_in[3] universal_re: unused (BETA=0)
    const float* W0s = (const float*)d_in[4];
    const float* b0s = (const float*)d_in[5];
    const float* W1s = (const float*)d_in[6];
    const float* b1s = (const float*)d_in[7];
    const float* W0l = (const float*)d_in[8];
    const float* b0l = (const float*)d_in[9];
    const float* W1l = (const float*)d_in[10];
    const float* b1l = (const float*)d_in[11];
    const float* W0h = (const float*)d_in[12];
    const float* b0h = (const float*)d_in[13];
    const float* W1h = (const float*)d_in[14];
    const float* b1h = (const float*)d_in[15];
    const float* amp = (const float*)d_in[16];
    const float* ahp = (const float*)d_in[17];

    float* out = (float*)d_out;                       // f32 output (ref dtype)
    float* ws = (float*)d_ws;
    float* emb = ws;                                  // NN*64 f32
    float* ut  = ws + (size_t)NN * DOUT;              // 64*NN f32 (u transposed)
    double* colsum = (double*)(ws + (size_t)2 * NN * DOUT);   // 64 f64 (=128 f32)
    unsigned int* mx = (unsigned int*)(ws + (size_t)2 * NN * DOUT + 128);
    float* scal = ws + (size_t)2 * NN * DOUT + 128 + 4;       // 3 f32
    size_t R_off = (((size_t)2 * NN * DOUT + 128 + 8) + 15) & ~(size_t)15;
    float* R = ws + R_off;

    // How many R rows fit in the remaining workspace?
    size_t ws_f = ws_size / 4;
    size_t avail = (ws_f > R_off) ? (ws_f - R_off) : 0;
    int sr = (int)((avail / NN) / 64) * 64;           // rows per strip, x64
    if (sr < 64) sr = 64;                              // minimal strip (1.5 MB)
    if (sr > NN) sr = NN;
    const int nstrips = (NN + sr - 1) / sr;

    hipMemsetAsync(mx, 0, 4, stream);
    mlp_kernel<<<dim3(NN / 8, 3), 256, 0, stream>>>(
        ori, sm, W0s, b0s, W1s, b1s, W0l, b0l, W1l, b1l,
        W0h, b0h, W1h, b1h, amp, ahp, out, emb, ut);
    colsum_kernel<<<64, 256, 0, stream>>>(ut, colsum);

    float* out3 = out + (size_t)2 * NN * DOUT;
    if (nstrips == 1) {
        r_gemm_kernel<<<dim3(96, 96), 256, 0, stream>>>(ut, R, mx, 0, 1, 1, 1);
        finalize_kernel<<<1, 64, 0, stream>>>(colsum, mx, scal);
        prop2_kernel<<<NN / 8, 256, 0, stream>>>(R, emb, scal, ahp, out3, 0);
    } else {
        r_gemm_kernel<<<dim3(96, 96), 256, 0, stream>>>(ut, R, mx, 0, 1, 0, 1);
        finalize_kernel<<<1, 64, 0, stream>>>(colsum, mx, scal);
        for (int s = 0; s < nstrips; ++s) {
            const int row0 = s * sr;
            const int rows = (NN - row0 < sr) ? (NN - row0) : sr;
            r_gemm_kernel<<<dim3(rows / 64, 96), 256, 0, stream>>>(
                ut, R, mx, row0, 0, 1, 0);
            prop2_kernel<<<rows / 8, 256, 0, stream>>>(
                R, emb, scal, ahp, out3, row0);
        }
    }
}

// Round 7
// 281.068 us; speedup vs baseline: 3.6520x; 1.4571x over previous
//
#include <hip/hip_runtime.h>
#include <hip/hip_bf16.h>

#define NN 6144
#define FEATN 128
#define INSM 512
#define HIDN 256
#define DOUT 64

typedef _Float16 h4v __attribute__((ext_vector_type(4)));
typedef _Float16 h8v __attribute__((ext_vector_type(8)));
typedef float f32x4 __attribute__((ext_vector_type(4)));

// ---------------------------------------------------------------------------
// Branch MLPs: out = prelu(X@W0+b0, a) @ W1 + b1.   (outputs FLOAT32)
// blockIdx.y: 0 = local(ori)->out0, 1 = smooth->out1, 2 = hete->emb, ut (ws)
// br==2 writes u TRANSPOSED: ut[64][6144] (ut[c][i] = u[i][c]).
// ---------------------------------------------------------------------------
__global__ __launch_bounds__(256) void mlp_kernel(
    const float* __restrict__ ori, const float* __restrict__ sm,
    const float* __restrict__ W0s, const float* __restrict__ b0s,
    const float* __restrict__ W1s, const float* __restrict__ b1s,
    const float* __restrict__ W0l, const float* __restrict__ b0l,
    const float* __restrict__ W1l, const float* __restrict__ b1l,
    const float* __restrict__ W0h, const float* __restrict__ b0h,
    const float* __restrict__ W1h, const float* __restrict__ b1h,
    const float* __restrict__ am_p, const float* __restrict__ ah_p,
    float* __restrict__ out, float* __restrict__ emb, float* __restrict__ ut)
{
    __shared__ float xs[8 * INSM];
    __shared__ float hs[8 * HIDN];
    __shared__ float vals[8 * DOUT];
    const int t = threadIdx.x;
    const int br = blockIdx.y;
    const int r0 = blockIdx.x * 8;

    const float *X, *W0, *b0, *W1, *b1;
    int IN;
    float alpha;
    if (br == 0)      { X = ori; W0 = W0l; b0 = b0l; W1 = W1l; b1 = b1l; IN = FEATN; alpha = am_p[0]; }
    else if (br == 1) { X = sm;  W0 = W0s; b0 = b0s; W1 = W1s; b1 = b1s; IN = INSM;  alpha = am_p[0]; }
    else              { X = sm;  W0 = W0h; b0 = b0h; W1 = W1h; b1 = b1h; IN = INSM;  alpha = ah_p[0]; }

    const float* Xb = X + (size_t)r0 * IN;
    const int tot4 = (8 * IN) >> 2;
    for (int i = t; i < tot4; i += 256)
        reinterpret_cast<float4*>(xs)[i] = reinterpret_cast<const float4*>(Xb)[i];
    __syncthreads();

    float acc[8];
    #pragma unroll
    for (int r = 0; r < 8; ++r) acc[r] = 0.f;
    for (int k = 0; k < IN; k += 4) {
        const float w0 = W0[(k + 0) * HIDN + t];
        const float w1 = W0[(k + 1) * HIDN + t];
        const float w2 = W0[(k + 2) * HIDN + t];
        const float w3 = W0[(k + 3) * HIDN + t];
        #pragma unroll
        for (int r = 0; r < 8; ++r) {
            float4 x4 = *reinterpret_cast<const float4*>(&xs[r * IN + k]);
            acc[r] = fmaf(x4.x, w0, acc[r]);
            acc[r] = fmaf(x4.y, w1, acc[r]);
            acc[r] = fmaf(x4.z, w2, acc[r]);
            acc[r] = fmaf(x4.w, w3, acc[r]);
        }
    }
    {
        float bb = b0[t];
        #pragma unroll
        for (int r = 0; r < 8; ++r) {
            float h = acc[r] + bb;
            hs[r * HIDN + t] = (h >= 0.f) ? h : alpha * h;
        }
    }
    __syncthreads();

    for (int task = t; task < 512; task += 256) {
        const int r = task >> 6, c = task & 63;
        float a2 = b1[c];
        for (int k = 0; k < HIDN; k += 4) {
            float4 h4 = *reinterpret_cast<const float4*>(&hs[r * HIDN + k]);
            a2 = fmaf(h4.x, W1[(k + 0) * DOUT + c], a2);
            a2 = fmaf(h4.y, W1[(k + 1) * DOUT + c], a2);
            a2 = fmaf(h4.z, W1[(k + 2) * DOUT + c], a2);
            a2 = fmaf(h4.w, W1[(k + 3) * DOUT + c], a2);
        }
        if (br < 2) {
            float* dst = out + (size_t)br * NN * DOUT;
            dst[(size_t)(r0 + r) * DOUT + c] = a2;
        } else {
            vals[r * DOUT + c] = a2;
        }
    }
    if (br == 2) {
        __syncthreads();
        const int wv = t >> 6, lane = t & 63;
        #pragma unroll
        for (int rep = 0; rep < 2; ++rep) {
            const int row = wv * 2 + rep;
            float v = vals[row * DOUT + lane];
            float mv = v;
            for (int off = 32; off > 0; off >>= 1) mv = fmaxf(mv, __shfl_xor(mv, off));
            float e = expf(v - mv);
            float ssum = e;
            for (int off = 32; off > 0; off >>= 1) ssum += __shfl_xor(ssum, off);
            float s = e / ssum;
            float n2 = s * s;
            for (int off = 32; off > 0; off >>= 1) n2 += __shfl_xor(n2, off);
            float uu = s * rsqrtf(n2);        // d_i >= 1/64 so max(.,1e-9) never binds
            emb[(size_t)(r0 + row) * DOUT + lane] = v;
            ut[(size_t)lane * NN + (r0 + row)] = uu;   // transposed scatter
        }
    }
}

// ---------------------------------------------------------------------------
// Column sums of u (= row sums of ut) in f64: one block per column c.
// ---------------------------------------------------------------------------
__global__ __launch_bounds__(256) void colsum_kernel(const float* __restrict__ ut,
                                                     double* __restrict__ colsum)
{
    __shared__ double cred[4];
    const int c = blockIdx.x, t = threadIdx.x;
    double a = 0.0;
    for (int i = t; i < NN; i += 256) a += (double)ut[(size_t)c * NN + i];
    for (int off = 32; off > 0; off >>= 1) a += __shfl_xor(a, off);
    if ((t & 63) == 0) cred[t >> 6] = a;
    __syncthreads();
    if (t == 0) colsum[c] = cred[0] + cred[1] + cred[2] + cred[3];
}

// ---------------------------------------------------------------------------
// R = u u^T tile GEMM, optionally storing R and/or accumulating max(off-diag).
// ---------------------------------------------------------------------------
__global__ __launch_bounds__(256) void r_gemm_kernel(
    const float* __restrict__ ut, float* __restrict__ R,
    unsigned int* __restrict__ mx,
    int row0, int sym, int do_store, int do_max)
{
    const int tix = blockIdx.x;            // strip-local i tile
    const int tj  = blockIdx.y;            // global j tile
    const int tig = (row0 >> 6) + tix;     // global i tile
    if (sym && tj < tig) return;
    __shared__ float uit[64 * 64];
    __shared__ float ujt[64 * 64];
    __shared__ float red[4];
    const int t = threadIdx.x;
    #pragma unroll
    for (int it = 0; it < 4; ++it) {
        const int p = t + it * 256;
        const int k = p >> 4, j4 = p & 15;
        *reinterpret_cast<float4*>(&uit[k * 64 + j4 * 4]) =
            *reinterpret_cast<const float4*>(&ut[(size_t)k * NN + tig * 64 + j4 * 4]);
        *reinterpret_cast<float4*>(&ujt[k * 64 + j4 * 4]) =
            *reinterpret_cast<const float4*>(&ut[(size_t)k * NN + tj * 64 + j4 * 4]);
    }
    __syncthreads();
    const int tx = t & 15, ty = t >> 4;
    float r16[16];
    #pragma unroll
    for (int s = 0; s < 16; ++s) r16[s] = 0.f;
    #pragma unroll 8
    for (int k = 0; k < 64; ++k) {
        float4 a4 = *reinterpret_cast<const float4*>(&uit[k * 64 + ty * 4]);
        float4 b4 = *reinterpret_cast<const float4*>(&ujt[k * 64 + tx * 4]);
        float av[4] = {a4.x, a4.y, a4.z, a4.w};
        float bv[4] = {b4.x, b4.y, b4.z, b4.w};
        #pragma unroll
        for (int aa = 0; aa < 4; ++aa)
            #pragma unroll
            for (int bb = 0; bb < 4; ++bb)
                r16[aa * 4 + bb] = fmaf(av[aa], bv[bb], r16[aa * 4 + bb]);
    }
    if (do_store) {
        #pragma unroll
        for (int aa = 0; aa < 4; ++aa) {
            float4 vv;
            vv.x = r16[aa * 4 + 0]; vv.y = r16[aa * 4 + 1];
            vv.z = r16[aa * 4 + 2]; vv.w = r16[aa * 4 + 3];
            *reinterpret_cast<float4*>(
                &R[(size_t)(tix * 64 + ty * 4 + aa) * NN + tj * 64 + tx * 4]) = vv;
        }
        if (sym && tj != tig) {
            #pragma unroll
            for (int bb = 0; bb < 4; ++bb) {
                float4 vv;
                vv.x = r16[0 * 4 + bb]; vv.y = r16[1 * 4 + bb];
                vv.z = r16[2 * 4 + bb]; vv.w = r16[3 * 4 + bb];
                *reinterpret_cast<float4*>(
                    &R[(size_t)(tj * 64 + tx * 4 + bb) * NN + tig * 64 + ty * 4]) = vv;
            }
        }
    }
    if (do_max) {
        float lm = 0.f;
        #pragma unroll
        for (int aa = 0; aa < 4; ++aa)
            #pragma unroll
            for (int bb = 0; bb < 4; ++bb) {
                const int gi = tig * 64 + ty * 4 + aa;
                const int gj = tj * 64 + tx * 4 + bb;
                if (gi != gj) lm = fmaxf(lm, r16[aa * 4 + bb]);
            }
        for (int off = 32; off > 0; off >>= 1) lm = fmaxf(lm, __shfl_xor(lm, off));
        if ((t & 63) == 0) red[t >> 6] = lm;
        __syncthreads();
        if (t == 0) {
            float bm = fmaxf(fmaxf(red[0], red[1]), fmaxf(red[2], red[3]));
            atomicMax(mx, __float_as_uint(bm));   // all candidates > 0
        }
    }
}

__global__ void finalize_kernel(const double* __restrict__ colsum,
                                const unsigned int* __restrict__ mx,
                                float* __restrict__ scal)
{
    const int c = threadIdx.x;   // 64 threads = 1 wave
    double cs = colsum[c];
    double s2 = cs * cs;
    for (int off = 32; off > 0; off >>= 1) s2 += __shfl_xor(s2, off);
    if (c == 0) {
        double md = (s2 - (double)NN) / ((double)NN * (double)NN);
        float mf = (float)md;
        float mxv = __uint_as_float(mx[0]);
        scal[0] = mf;
        scal[1] = 1.0f / (mxv - mf);
        scal[2] = 1.0f / mf;
    }
}

// ---------------------------------------------------------------------------
// emb -> fp16 hi/lo, k-major packed for MFMA B-fragments:
// element (j, c) -> ehi[((j>>3)*64 + c)*8 + (j&7)]  (8 consecutive j = 16 B).
// ---------------------------------------------------------------------------
__global__ __launch_bounds__(256) void emb_split_kernel(
    const float* __restrict__ emb, _Float16* __restrict__ ehi,
    _Float16* __restrict__ elo)
{
    const int idx = blockIdx.x * 256 + threadIdx.x;   // jblk*64 + c, < 49152
    const int c = idx & 63, jblk = idx >> 6;
    h8v hi, lo;
    #pragma unroll
    for (int e = 0; e < 8; ++e) {
        float x = emb[(size_t)(jblk * 8 + e) * 64 + c];
        _Float16 h = (_Float16)x;
        hi[e] = h;
        lo[e] = (_Float16)(x - (float)h);
    }
    *reinterpret_cast<h8v*>(&ehi[(size_t)idx * 8]) = hi;
    *reinterpret_cast<h8v*>(&elo[(size_t)idx * 8]) = lo;
}

// ---------------------------------------------------------------------------
// Propagation v3 (MFMA): 16 rows/block, 256 threads (4 waves).
// Per 64-j tile: all threads load R quads from global, transform -> v, p=prelu(v),
// split to fp16 hi/lo, write 4 LDS A-arrays [16][64] (granule-XOR swizzled,
// double-buffered). Each wave owns C-columns w*16..+15 and accumulates
//   P += phi*Bhi + phi*Blo + plo*Bhi ;  L += vhi*Bhi + vhi*Blo + vlo*Bhi
// via v_mfma_f32_16x16x32_f16. Then N = P - (1+alpha)*L, softmax, epilogue.
// A-frag: row=lane&15, k=(lane>>4)*8+e. C/D: col=lane&15, row=(lane>>4)*4+reg.
// ---------------------------------------------------------------------------
__global__ __launch_bounds__(256) void prop3_kernel(
    const float* __restrict__ R, const float* __restrict__ emb,
    const _Float16* __restrict__ ehi, const _Float16* __restrict__ elo,
    const float* __restrict__ scal, const float* __restrict__ ah_p,
    float* __restrict__ out3, int row0)
{
    __shared__ _Float16 Abuf[2][4][1024];   // [buf][vhi,vlo,phi,plo][16x64 swz]
    __shared__ float smx[2][16][68];        // P and N logits for softmax

    const int t = threadIdx.x;
    const int bi = blockIdx.x;              // strip-local, rows bi*16..+15
    const int gi0 = row0 + bi * 16;
    const float m = scal[0], inv_pd = scal[1], inv_m = scal[2];
    const float alpha = ah_p[0];

    // producer role
    const int prow = t >> 4, pq = t & 15;
    const int pbyte = prow * 128 + ((((pq >> 1) ^ (prow & 7)) << 4)) + ((pq & 1) << 3);
    const int gi_p = gi0 + prow;

    // consumer role
    const int w = t >> 6, l = t & 63;
    const int arow = l & 15, ag = l >> 4;
    const int bcol = w * 16 + arow;

    f32x4 accP = {0.f, 0.f, 0.f, 0.f};
    f32x4 accL = {0.f, 0.f, 0.f, 0.f};

    const float* Rrow = &R[(size_t)(bi * 16 + prow) * NN + pq * 4];
    float4 r4 = *reinterpret_cast<const float4*>(Rrow);

    for (int jt = 0; jt < 96; ++jt) {
        const int buf = jt & 1;
        // ---- producer: transform + fp16 split + LDS write ----
        {
            h4v vhi4, vlo4, phi4, plo4;
            float rr[4] = {r4.x, r4.y, r4.z, r4.w};
            #pragma unroll
            for (int s = 0; s < 4; ++s) {
                const int gj = jt * 64 + pq * 4 + s;
                float lre = (gi_p == gj) ? 0.f : rr[s];
                float x = lre - m;
                float v = (x > 0.f) ? x * inv_pd : -(lre * inv_m);
                if (gi_p == gj) v += 1.f;          // add_diag after where
                float p = (v >= 0.f) ? v : alpha * v;
                _Float16 vh = (_Float16)v;
                _Float16 ph = (_Float16)p;
                vhi4[s] = vh; vlo4[s] = (_Float16)(v - (float)vh);
                phi4[s] = ph; plo4[s] = (_Float16)(p - (float)ph);
            }
            char* base = (char*)&Abuf[buf][0][0];
            *reinterpret_cast<h4v*>(base + pbyte) = vhi4;
            *reinterpret_cast<h4v*>(base + 2048 + pbyte) = vlo4;
            *reinterpret_cast<h4v*>(base + 4096 + pbyte) = phi4;
            *reinterpret_cast<h4v*>(base + 6144 + pbyte) = plo4;
        }
        // prefetch next R quad (latency hidden under barrier + MFMA phase)
        if (jt + 1 < 96)
            r4 = *reinterpret_cast<const float4*>(Rrow + (jt + 1) * 64);
        __syncthreads();

        // ---- consumer: 2 K-steps of MFMA ----
        const char* base = (const char*)&Abuf[buf][0][0];
        #pragma unroll
        for (int ks = 0; ks < 2; ++ks) {
            const int abyte = arow * 128 + ((((ks * 4 + ag) ^ (arow & 7)) << 4));
            h8v vhiF = *reinterpret_cast<const h8v*>(base + abyte);
            h8v vloF = *reinterpret_cast<const h8v*>(base + 2048 + abyte);
            h8v phiF = *reinterpret_cast<const h8v*>(base + 4096 + abyte);
            h8v ploF = *reinterpret_cast<const h8v*>(base + 6144 + abyte);
            const size_t bidx = ((size_t)(jt * 8 + ks * 4 + ag) * 64 + bcol) * 8;
            h8v Bhi = *reinterpret_cast<const h8v*>(&ehi[bidx]);
            h8v Blo = *reinterpret_cast<const h8v*>(&elo[bidx]);
            accP = __builtin_amdgcn_mfma_f32_16x16x32_f16(phiF, Bhi, accP, 0, 0, 0);
            accP = __builtin_amdgcn_mfma_f32_16x16x32_f16(phiF, Blo, accP, 0, 0, 0);
            accP = __builtin_amdgcn_mfma_f32_16x16x32_f16(ploF, Bhi, accP, 0, 0, 0);
            accL = __builtin_amdgcn_mfma_f32_16x16x32_f16(vhiF, Bhi, accL, 0, 0, 0);
            accL = __builtin_amdgcn_mfma_f32_16x16x32_f16(vhiF, Blo, accL, 0, 0, 0);
            accL = __builtin_amdgcn_mfma_f32_16x16x32_f16(vloF, Bhi, accL, 0, 0, 0);
        }
    }

    // ---- epilogue: N = P - (1+alpha) L, cross-wave softmax ----
    {
        const float one_pa = 1.f + alpha;
        #pragma unroll
        for (int r = 0; r < 4; ++r) {
            const int row = ag * 4 + r;
            smx[0][row][bcol] = accP[r];
            smx[1][row][bcol] = accP[r] - one_pa * accL[r];
        }
    }
    __syncthreads();
    #pragma unroll
    for (int rr = 0; rr < 4; ++rr) {
        const int row = w * 4 + rr;
        float zp = smx[0][row][l];
        float mp = zp;
        for (int off = 32; off > 0; off >>= 1) mp = fmaxf(mp, __shfl_xor(mp, off));
        float ep = __expf(zp - mp);
        float sump = ep;
        for (int off = 32; off > 0; off >>= 1) sump += __shfl_xor(sump, off);
        float pp = ep / sump;

        float zn = smx[1][row][l];
        float mn = zn;
        for (int off = 32; off > 0; off >>= 1) mn = fmaxf(mn, __shfl_xor(mn, off));
        float en = __expf(zn - mn);
        float sumn = en;
        for (int off = 32; off > 0; off >>= 1) sumn += __shfl_xor(sumn, off);
        float pn = en / sumn;

        const size_t gi = (size_t)gi0 + row;
        out3[gi * 64 + l] = 0.5f * (pp - pn + emb[gi * 64 + l]);
    }
}

extern "C" void kernel_launch(void* const* d_in, const int* in_sizes, int n_in,
                              void* d_out, int out_size, void* d_ws, size_t ws_size,
                              hipStream_t stream)
{
    (void)in_sizes; (void)n_in; (void)out_size;
    const float* ori = (const float*)d_in[0];
    const float* sm  = (const float*)d_in[1];
    // d_in[2] processed_feature: unused; d_in[3] universal_re: unused (BETA=0)
    const float* W0s = (const float*)d_in[4];
    const float* b0s = (const float*)d_in[5];
    const float* W1s = (const float*)d_in[6];
    const float* b1s = (const float*)d_in[7];
    const float* W0l = (const float*)d_in[8];
    const float* b0l = (const float*)d_in[9];
    const float* W1l = (const float*)d_in[10];
    const float* b1l = (const float*)d_in[11];
    const float* W0h = (const float*)d_in[12];
    const float* b0h = (const float*)d_in[13];
    const float* W1h = (const float*)d_in[14];
    const float* b1h = (const float*)d_in[15];
    const float* amp = (const float*)d_in[16];
    const float* ahp = (const float*)d_in[17];

    float* out = (float*)d_out;                       // f32 output (ref dtype)
    float* ws = (float*)d_ws;
    float* emb = ws;                                  // NN*64 f32
    float* ut  = ws + (size_t)NN * DOUT;              // 64*NN f32 (u transposed)
    double* colsum = (double*)(ws + (size_t)2 * NN * DOUT);   // 64 f64
    unsigned int* mx = (unsigned int*)(ws + (size_t)2 * NN * DOUT + 128);
    float* scal = ws + (size_t)2 * NN * DOUT + 128 + 4;       // 3 f32
    size_t eh_off = (((size_t)2 * NN * DOUT + 128 + 8) + 15) & ~(size_t)15;
    _Float16* ehi = (_Float16*)(ws + eh_off);                 // NN*64 halves
    _Float16* elo = (_Float16*)(ws + eh_off + (size_t)NN * DOUT / 2);
    size_t R_off = eh_off + (size_t)NN * DOUT;                // after hi+lo
    float* R = ws + R_off;

    // How many R rows fit in the remaining workspace?
    size_t ws_f = ws_size / 4;
    size_t avail = (ws_f > R_off) ? (ws_f - R_off) : 0;
    int sr = (int)((avail / NN) / 64) * 64;           // rows per strip, x64
    if (sr < 64) sr = 64;                              // minimal strip (1.5 MB)
    if (sr > NN) sr = NN;
    const int nstrips = (NN + sr - 1) / sr;

    hipMemsetAsync(mx, 0, 4, stream);
    mlp_kernel<<<dim3(NN / 8, 3), 256, 0, stream>>>(
        ori, sm, W0s, b0s, W1s, b1s, W0l, b0l, W1l, b1l,
        W0h, b0h, W1h, b1h, amp, ahp, out, emb, ut);
    colsum_kernel<<<64, 256, 0, stream>>>(ut, colsum);
    emb_split_kernel<<<NN * DOUT / 8 / 64 / 4, 256, 0, stream>>>(emb, ehi, elo);

    float* out3 = out + (size_t)2 * NN * DOUT;
    if (nstrips == 1) {
        r_gemm_kernel<<<dim3(96, 96), 256, 0, stream>>>(ut, R, mx, 0, 1, 1, 1);
        finalize_kernel<<<1, 64, 0, stream>>>(colsum, mx, scal);
        prop3_kernel<<<NN / 16, 256, 0, stream>>>(R, emb, ehi, elo, scal, ahp, out3, 0);
    } else {
        r_gemm_kernel<<<dim3(96, 96), 256, 0, stream>>>(ut, R, mx, 0, 1, 0, 1);
        finalize_kernel<<<1, 64, 0, stream>>>(colsum, mx, scal);
        for (int s = 0; s < nstrips; ++s) {
            const int row0 = s * sr;
            const int rows = (NN - row0 < sr) ? (NN - row0) : sr;
            r_gemm_kernel<<<dim3(rows / 64, 96), 256, 0, stream>>>(
                ut, R, mx, row0, 0, 1, 0);
            prop3_kernel<<<rows / 16, 256, 0, stream>>>(
                R, emb, ehi, elo, scal, ahp, out3, row0);
        }
    }
}

// Round 8
// 229.786 us; speedup vs baseline: 4.4670x; 1.2232x over previous
//
#include <hip/hip_runtime.h>
#include <hip/hip_bf16.h>

#define NN 6144
#define FEATN 128
#define INSM 512
#define HIDN 256
#define DOUT 64

typedef _Float16 h4v __attribute__((ext_vector_type(4)));
typedef _Float16 h8v __attribute__((ext_vector_type(8)));
typedef float f32x4 __attribute__((ext_vector_type(4)));

// Weight-pack offsets (in halves) inside the contiguous wpk buffer.
#define O_W0L 0         // 128x256 -> hi at 0, lo at +32768
#define O_W0S 65536     // 512x256 -> hi, lo at +131072
#define O_W0H 327680
#define O_W1L 589824    // 256x64 -> hi, lo at +16384
#define O_W1S 622592
#define O_W1H 655360
#define WPK_HALVES 688128

// ---------------------------------------------------------------------------
// Pack the 6 weight matrices to fp16 hi/lo in MFMA B-fragment k-major layout:
// element (k, col) -> pk[off + (kblk*N + col)*8 + (k&7)], kblk = k>>3.
// ---------------------------------------------------------------------------
__global__ __launch_bounds__(256) void pack_w_kernel(
    const float* __restrict__ W0l, const float* __restrict__ W0s_,
    const float* __restrict__ W0h, const float* __restrict__ W1l,
    const float* __restrict__ W1s_, const float* __restrict__ W1h,
    _Float16* __restrict__ pk)
{
    const int id = blockIdx.y;
    const float* src; int K, N, offhi;
    switch (id) {
        case 0:  src = W0l;  K = 128; N = 256; offhi = O_W0L; break;
        case 1:  src = W0s_; K = 512; N = 256; offhi = O_W0S; break;
        case 2:  src = W0h;  K = 512; N = 256; offhi = O_W0H; break;
        case 3:  src = W1l;  K = 256; N = 64;  offhi = O_W1L; break;
        case 4:  src = W1s_; K = 256; N = 64;  offhi = O_W1S; break;
        default: src = W1h;  K = 256; N = 64;  offhi = O_W1H; break;
    }
    const int cnt = (K * N) >> 3;
    const int idx = blockIdx.x * 256 + threadIdx.x;
    if (idx >= cnt) return;
    const int col  = (N == 256) ? (idx & 255) : (idx & 63);
    const int kblk = (N == 256) ? (idx >> 8) : (idx >> 6);
    h8v hi, lo;
    #pragma unroll
    for (int e = 0; e < 8; ++e) {
        float x = src[(size_t)(kblk * 8 + e) * N + col];
        _Float16 h = (_Float16)x;
        hi[e] = h;
        lo[e] = (_Float16)(x - (float)h);
    }
    *reinterpret_cast<h8v*>(&pk[(size_t)offhi + (size_t)idx * 8]) = hi;
    *reinterpret_cast<h8v*>(&pk[(size_t)offhi + (size_t)(K * N) + (size_t)idx * 8]) = lo;
}

// ---------------------------------------------------------------------------
// MFMA MLP: out = prelu(X@W0+b0, a) @ W1 + b1, all three branches.
// grid (96, 3), block 256 (4 waves). Block = 64 rows; wave owns a 64-col
// slice of layer1 (16 fragments) and a 16-col slice of layer2 (4 fragments).
// fp16 split-precision (hi*hi + hi*lo + lo*hi, f32 accumulate).
// br==2 epilogue: row softmax + L2 normalize -> emb, ut (transposed).
// LDS: X slab dbuf (16 KB) aliased inside H (64x264 f32, 66 KB) and vals.
// ---------------------------------------------------------------------------
__global__ __launch_bounds__(256) void mlp2_kernel(
    const float* __restrict__ ori, const float* __restrict__ sm,
    const _Float16* __restrict__ pk,
    const float* __restrict__ b0l, const float* __restrict__ b0s,
    const float* __restrict__ b0h, const float* __restrict__ b1l,
    const float* __restrict__ b1s, const float* __restrict__ b1h,
    const float* __restrict__ am_p, const float* __restrict__ ah_p,
    float* __restrict__ out, float* __restrict__ emb, float* __restrict__ ut)
{
    __shared__ __align__(16) char smem[64 * 264 * 4];   // 67584 B
    float* xs   = (float*)smem;     // [2][64][32] dbuf, 16 KB (layer1 phase)
    float* hs   = (float*)smem;     // [64][264] f32 (layer2 phase)
    float* vals = (float*)smem;     // [64][65] f32 (br2 softmax phase)

    const int t = threadIdx.x;
    const int br = blockIdx.y;
    const int r0 = blockIdx.x * 64;
    const int w = t >> 6, lane = t & 63, arow = lane & 15, ag = lane >> 4;

    const float* X;
    const _Float16 *B0hi, *B0lo, *B1hi, *B1lo;
    const float *bias0, *bias1;
    int K1; float alpha;
    if (br == 0) {
        X = ori; B0hi = pk + O_W0L; B0lo = B0hi + 128 * 256;
        B1hi = pk + O_W1L; B1lo = B1hi + 256 * 64;
        bias0 = b0l; bias1 = b1l; K1 = FEATN; alpha = am_p[0];
    } else if (br == 1) {
        X = sm; B0hi = pk + O_W0S; B0lo = B0hi + 512 * 256;
        B1hi = pk + O_W1S; B1lo = B1hi + 256 * 64;
        bias0 = b0s; bias1 = b1s; K1 = INSM; alpha = am_p[0];
    } else {
        X = sm; B0hi = pk + O_W0H; B0lo = B0hi + 512 * 256;
        B1hi = pk + O_W1H; B1lo = B1hi + 256 * 64;
        bias0 = b0h; bias1 = b1h; K1 = INSM; alpha = ah_p[0];
    }
    const int nks = K1 >> 5;

    // ---- layer 1: H[64][256] = prelu(X@W0 + b0) ----
    const int srow = t >> 2, sseg = t & 3;           // staging: 4 thr/row
    const float* Xrow = X + (size_t)(r0 + srow) * K1 + sseg * 8;

    {   // stage ks = 0
        float4 a = *reinterpret_cast<const float4*>(Xrow);
        float4 b = *reinterpret_cast<const float4*>(Xrow + 4);
        float* p = &xs[(0 * 64 + srow) * 32 + sseg * 8];
        *reinterpret_cast<float4*>(p) = a;
        *reinterpret_cast<float4*>(p + 4) = b;
    }
    __syncthreads();

    f32x4 acc1[4][4] = {};                            // [rowtile][coltile]
    for (int ks = 0; ks < nks; ++ks) {
        const int buf = ks & 1;
        if (ks + 1 < nks) {                           // stage next slab
            const float* g = Xrow + (ks + 1) * 32;
            float4 a = *reinterpret_cast<const float4*>(g);
            float4 b = *reinterpret_cast<const float4*>(g + 4);
            float* p = &xs[((buf ^ 1) * 64 + srow) * 32 + sseg * 8];
            *reinterpret_cast<float4*>(p) = a;
            *reinterpret_cast<float4*>(p + 4) = b;
        }
        h8v ahi[4], alo[4];
        #pragma unroll
        for (int rt = 0; rt < 4; ++rt) {              // A-frags, split hi/lo
            const float* ap = &xs[(buf * 64 + rt * 16 + arow) * 32 + ag * 8];
            float4 a = *reinterpret_cast<const float4*>(ap);
            float4 b = *reinterpret_cast<const float4*>(ap + 4);
            float fv[8] = {a.x, a.y, a.z, a.w, b.x, b.y, b.z, b.w};
            #pragma unroll
            for (int e = 0; e < 8; ++e) {
                _Float16 h = (_Float16)fv[e];
                ahi[rt][e] = h;
                alo[rt][e] = (_Float16)(fv[e] - (float)h);
            }
        }
        #pragma unroll
        for (int ct = 0; ct < 4; ++ct) {
            const size_t bidx =
                ((size_t)(ks * 4 + ag) * 256 + w * 64 + ct * 16 + arow) * 8;
            h8v bhi = *reinterpret_cast<const h8v*>(&B0hi[bidx]);
            h8v blo = *reinterpret_cast<const h8v*>(&B0lo[bidx]);
            #pragma unroll
            for (int rt = 0; rt < 4; ++rt) {
                acc1[rt][ct] = __builtin_amdgcn_mfma_f32_16x16x32_f16(ahi[rt], bhi, acc1[rt][ct], 0, 0, 0);
                acc1[rt][ct] = __builtin_amdgcn_mfma_f32_16x16x32_f16(ahi[rt], blo, acc1[rt][ct], 0, 0, 0);
                acc1[rt][ct] = __builtin_amdgcn_mfma_f32_16x16x32_f16(alo[rt], bhi, acc1[rt][ct], 0, 0, 0);
            }
        }
        __syncthreads();                              // slab reads done
    }

    // epilogue L1: bias + prelu -> hs (xs is dead; hs aliases it)
    #pragma unroll
    for (int ct = 0; ct < 4; ++ct) {
        const int col = w * 64 + ct * 16 + arow;
        const float bb = bias0[col];
        #pragma unroll
        for (int rt = 0; rt < 4; ++rt)
            #pragma unroll
            for (int r = 0; r < 4; ++r) {
                float h = acc1[rt][ct][r] + bb;       // C/D row = ag*4+r
                hs[(rt * 16 + ag * 4 + r) * 264 + col] = (h >= 0.f) ? h : alpha * h;
            }
    }
    __syncthreads();

    // ---- layer 2: O[64][64] = H@W1 + b1 (K=256, 8 K-steps) ----
    f32x4 acc2[4] = {};
    #pragma unroll
    for (int ks2 = 0; ks2 < 8; ++ks2) {
        const size_t bidx = ((size_t)(ks2 * 4 + ag) * 64 + w * 16 + arow) * 8;
        h8v bhi = *reinterpret_cast<const h8v*>(&B1hi[bidx]);
        h8v blo = *reinterpret_cast<const h8v*>(&B1lo[bidx]);
        #pragma unroll
        for (int rt = 0; rt < 4; ++rt) {
            const float* ap = &hs[(rt * 16 + arow) * 264 + ks2 * 32 + ag * 8];
            float4 a = *reinterpret_cast<const float4*>(ap);
            float4 b = *reinterpret_cast<const float4*>(ap + 4);
            float fv[8] = {a.x, a.y, a.z, a.w, b.x, b.y, b.z, b.w};
            h8v ahi8, alo8;
            #pragma unroll
            for (int e = 0; e < 8; ++e) {
                _Float16 h = (_Float16)fv[e];
                ahi8[e] = h;
                alo8[e] = (_Float16)(fv[e] - (float)h);
            }
            acc2[rt] = __builtin_amdgcn_mfma_f32_16x16x32_f16(ahi8, bhi, acc2[rt], 0, 0, 0);
            acc2[rt] = __builtin_amdgcn_mfma_f32_16x16x32_f16(ahi8, blo, acc2[rt], 0, 0, 0);
            acc2[rt] = __builtin_amdgcn_mfma_f32_16x16x32_f16(alo8, bhi, acc2[rt], 0, 0, 0);
        }
    }

    const int col2 = w * 16 + arow;
    const float bb1 = bias1[col2];
    if (br < 2) {
        float* dst = out + (size_t)br * NN * DOUT;
        #pragma unroll
        for (int rt = 0; rt < 4; ++rt)
            #pragma unroll
            for (int r = 0; r < 4; ++r)
                dst[(size_t)(r0 + rt * 16 + ag * 4 + r) * 64 + col2] =
                    acc2[rt][r] + bb1;
    } else {
        __syncthreads();                              // hs reads done; vals aliases
        #pragma unroll
        for (int rt = 0; rt < 4; ++rt)
            #pragma unroll
            for (int r = 0; r < 4; ++r)
                vals[(rt * 16 + ag * 4 + r) * 65 + col2] = acc2[rt][r] + bb1;
        __syncthreads();
        // row softmax (64 lanes) + L2 normalize; wave w owns rows w*16..+15
        for (int rr = 0; rr < 16; ++rr) {
            const int row = w * 16 + rr;
            float v = vals[row * 65 + lane];
            float mv = v;
            for (int off = 32; off > 0; off >>= 1) mv = fmaxf(mv, __shfl_xor(mv, off));
            float e = expf(v - mv);
            float ssum = e;
            for (int off = 32; off > 0; off >>= 1) ssum += __shfl_xor(ssum, off);
            float s = e / ssum;
            float n2 = s * s;
            for (int off = 32; off > 0; off >>= 1) n2 += __shfl_xor(n2, off);
            float uu = s * rsqrtf(n2);    // d_i >= 1/64 so max(.,1e-9) never binds
            emb[(size_t)(r0 + row) * 64 + lane] = v;
            ut[(size_t)lane * NN + (r0 + row)] = uu;
        }
    }
}

// ---------------------------------------------------------------------------
// Column sums of u (= row sums of ut) in f64: one block per column c.
// ---------------------------------------------------------------------------
__global__ __launch_bounds__(256) void colsum_kernel(const float* __restrict__ ut,
                                                     double* __restrict__ colsum)
{
    __shared__ double cred[4];
    const int c = blockIdx.x, t = threadIdx.x;
    double a = 0.0;
    for (int i = t; i < NN; i += 256) a += (double)ut[(size_t)c * NN + i];
    for (int off = 32; off > 0; off >>= 1) a += __shfl_xor(a, off);
    if ((t & 63) == 0) cred[t >> 6] = a;
    __syncthreads();
    if (t == 0) colsum[c] = cred[0] + cred[1] + cred[2] + cred[3];
}

// ---------------------------------------------------------------------------
// R = u u^T tile GEMM, optionally storing R and/or accumulating max(off-diag).
// ---------------------------------------------------------------------------
__global__ __launch_bounds__(256) void r_gemm_kernel(
    const float* __restrict__ ut, float* __restrict__ R,
    unsigned int* __restrict__ mx,
    int row0, int sym, int do_store, int do_max)
{
    const int tix = blockIdx.x;            // strip-local i tile
    const int tj  = blockIdx.y;            // global j tile
    const int tig = (row0 >> 6) + tix;     // global i tile
    if (sym && tj < tig) return;
    __shared__ float uit[64 * 64];
    __shared__ float ujt[64 * 64];
    __shared__ float red[4];
    const int t = threadIdx.x;
    #pragma unroll
    for (int it = 0; it < 4; ++it) {
        const int p = t + it * 256;
        const int k = p >> 4, j4 = p & 15;
        *reinterpret_cast<float4*>(&uit[k * 64 + j4 * 4]) =
            *reinterpret_cast<const float4*>(&ut[(size_t)k * NN + tig * 64 + j4 * 4]);
        *reinterpret_cast<float4*>(&ujt[k * 64 + j4 * 4]) =
            *reinterpret_cast<const float4*>(&ut[(size_t)k * NN + tj * 64 + j4 * 4]);
    }
    __syncthreads();
    const int tx = t & 15, ty = t >> 4;
    float r16[16];
    #pragma unroll
    for (int s = 0; s < 16; ++s) r16[s] = 0.f;
    #pragma unroll 8
    for (int k = 0; k < 64; ++k) {
        float4 a4 = *reinterpret_cast<const float4*>(&uit[k * 64 + ty * 4]);
        float4 b4 = *reinterpret_cast<const float4*>(&ujt[k * 64 + tx * 4]);
        float av[4] = {a4.x, a4.y, a4.z, a4.w};
        float bv[4] = {b4.x, b4.y, b4.z, b4.w};
        #pragma unroll
        for (int aa = 0; aa < 4; ++aa)
            #pragma unroll
            for (int bb = 0; bb < 4; ++bb)
                r16[aa * 4 + bb] = fmaf(av[aa], bv[bb], r16[aa * 4 + bb]);
    }
    if (do_store) {
        #pragma unroll
        for (int aa = 0; aa < 4; ++aa) {
            float4 vv;
            vv.x = r16[aa * 4 + 0]; vv.y = r16[aa * 4 + 1];
            vv.z = r16[aa * 4 + 2]; vv.w = r16[aa * 4 + 3];
            *reinterpret_cast<float4*>(
                &R[(size_t)(tix * 64 + ty * 4 + aa) * NN + tj * 64 + tx * 4]) = vv;
        }
        if (sym && tj != tig) {
            #pragma unroll
            for (int bb = 0; bb < 4; ++bb) {
                float4 vv;
                vv.x = r16[0 * 4 + bb]; vv.y = r16[1 * 4 + bb];
                vv.z = r16[2 * 4 + bb]; vv.w = r16[3 * 4 + bb];
                *reinterpret_cast<float4*>(
                    &R[(size_t)(tj * 64 + tx * 4 + bb) * NN + tig * 64 + ty * 4]) = vv;
            }
        }
    }
    if (do_max) {
        float lm = 0.f;
        #pragma unroll
        for (int aa = 0; aa < 4; ++aa)
            #pragma unroll
            for (int bb = 0; bb < 4; ++bb) {
                const int gi = tig * 64 + ty * 4 + aa;
                const int gj = tj * 64 + tx * 4 + bb;
                if (gi != gj) lm = fmaxf(lm, r16[aa * 4 + bb]);
            }
        for (int off = 32; off > 0; off >>= 1) lm = fmaxf(lm, __shfl_xor(lm, off));
        if ((t & 63) == 0) red[t >> 6] = lm;
        __syncthreads();
        if (t == 0) {
            float bm = fmaxf(fmaxf(red[0], red[1]), fmaxf(red[2], red[3]));
            atomicMax(mx, __float_as_uint(bm));   // all candidates > 0
        }
    }
}

__global__ void finalize_kernel(const double* __restrict__ colsum,
                                const unsigned int* __restrict__ mx,
                                float* __restrict__ scal)
{
    const int c = threadIdx.x;   // 64 threads = 1 wave
    double cs = colsum[c];
    double s2 = cs * cs;
    for (int off = 32; off > 0; off >>= 1) s2 += __shfl_xor(s2, off);
    if (c == 0) {
        double md = (s2 - (double)NN) / ((double)NN * (double)NN);
        float mf = (float)md;
        float mxv = __uint_as_float(mx[0]);
        scal[0] = mf;
        scal[1] = 1.0f / (mxv - mf);
        scal[2] = 1.0f / mf;
    }
}

// ---------------------------------------------------------------------------
// emb -> fp16 hi/lo, k-major packed for MFMA B-fragments.
// ---------------------------------------------------------------------------
__global__ __launch_bounds__(256) void emb_split_kernel(
    const float* __restrict__ emb, _Float16* __restrict__ ehi,
    _Float16* __restrict__ elo)
{
    const int idx = blockIdx.x * 256 + threadIdx.x;   // jblk*64 + c, < 49152
    const int c = idx & 63, jblk = idx >> 6;
    h8v hi, lo;
    #pragma unroll
    for (int e = 0; e < 8; ++e) {
        float x = emb[(size_t)(jblk * 8 + e) * 64 + c];
        _Float16 h = (_Float16)x;
        hi[e] = h;
        lo[e] = (_Float16)(x - (float)h);
    }
    *reinterpret_cast<h8v*>(&ehi[(size_t)idx * 8]) = hi;
    *reinterpret_cast<h8v*>(&elo[(size_t)idx * 8]) = lo;
}

// ---------------------------------------------------------------------------
// Propagation (MFMA): 16 rows/block, 256 threads (4 waves). See round 7.
// ---------------------------------------------------------------------------
__global__ __launch_bounds__(256) void prop3_kernel(
    const float* __restrict__ R, const float* __restrict__ emb,
    const _Float16* __restrict__ ehi, const _Float16* __restrict__ elo,
    const float* __restrict__ scal, const float* __restrict__ ah_p,
    float* __restrict__ out3, int row0)
{
    __shared__ _Float16 Abuf[2][4][1024];   // [buf][vhi,vlo,phi,plo][16x64 swz]
    __shared__ float smx[2][16][68];        // P and N logits for softmax

    const int t = threadIdx.x;
    const int bi = blockIdx.x;              // strip-local, rows bi*16..+15
    const int gi0 = row0 + bi * 16;
    const float m = scal[0], inv_pd = scal[1], inv_m = scal[2];
    const float alpha = ah_p[0];

    const int prow = t >> 4, pq = t & 15;
    const int pbyte = prow * 128 + ((((pq >> 1) ^ (prow & 7)) << 4)) + ((pq & 1) << 3);
    const int gi_p = gi0 + prow;

    const int w = t >> 6, l = t & 63;
    const int arow = l & 15, ag = l >> 4;
    const int bcol = w * 16 + arow;

    f32x4 accP = {0.f, 0.f, 0.f, 0.f};
    f32x4 accL = {0.f, 0.f, 0.f, 0.f};

    const float* Rrow = &R[(size_t)(bi * 16 + prow) * NN + pq * 4];
    float4 r4 = *reinterpret_cast<const float4*>(Rrow);

    for (int jt = 0; jt < 96; ++jt) {
        const int buf = jt & 1;
        {
            h4v vhi4, vlo4, phi4, plo4;
            float rr[4] = {r4.x, r4.y, r4.z, r4.w};
            #pragma unroll
            for (int s = 0; s < 4; ++s) {
                const int gj = jt * 64 + pq * 4 + s;
                float lre = (gi_p == gj) ? 0.f : rr[s];
                float x = lre - m;
                float v = (x > 0.f) ? x * inv_pd : -(lre * inv_m);
                if (gi_p == gj) v += 1.f;          // add_diag after where
                float p = (v >= 0.f) ? v : alpha * v;
                _Float16 vh = (_Float16)v;
                _Float16 ph = (_Float16)p;
                vhi4[s] = vh; vlo4[s] = (_Float16)(v - (float)vh);
                phi4[s] = ph; plo4[s] = (_Float16)(p - (float)ph);
            }
            char* base = (char*)&Abuf[buf][0][0];
            *reinterpret_cast<h4v*>(base + pbyte) = vhi4;
            *reinterpret_cast<h4v*>(base + 2048 + pbyte) = vlo4;
            *reinterpret_cast<h4v*>(base + 4096 + pbyte) = phi4;
            *reinterpret_cast<h4v*>(base + 6144 + pbyte) = plo4;
        }
        if (jt + 1 < 96)
            r4 = *reinterpret_cast<const float4*>(Rrow + (jt + 1) * 64);
        __syncthreads();

        const char* base = (const char*)&Abuf[buf][0][0];
        #pragma unroll
        for (int ks = 0; ks < 2; ++ks) {
            const int abyte = arow * 128 + ((((ks * 4 + ag) ^ (arow & 7)) << 4));
            h8v vhiF = *reinterpret_cast<const h8v*>(base + abyte);
            h8v vloF = *reinterpret_cast<const h8v*>(base + 2048 + abyte);
            h8v phiF = *reinterpret_cast<const h8v*>(base + 4096 + abyte);
            h8v ploF = *reinterpret_cast<const h8v*>(base + 6144 + abyte);
            const size_t bidx = ((size_t)(jt * 8 + ks * 4 + ag) * 64 + bcol) * 8;
            h8v Bhi = *reinterpret_cast<const h8v*>(&ehi[bidx]);
            h8v Blo = *reinterpret_cast<const h8v*>(&elo[bidx]);
            accP = __builtin_amdgcn_mfma_f32_16x16x32_f16(phiF, Bhi, accP, 0, 0, 0);
            accP = __builtin_amdgcn_mfma_f32_16x16x32_f16(phiF, Blo, accP, 0, 0, 0);
            accP = __builtin_amdgcn_mfma_f32_16x16x32_f16(ploF, Bhi, accP, 0, 0, 0);
            accL = __builtin_amdgcn_mfma_f32_16x16x32_f16(vhiF, Bhi, accL, 0, 0, 0);
            accL = __builtin_amdgcn_mfma_f32_16x16x32_f16(vhiF, Blo, accL, 0, 0, 0);
            accL = __builtin_amdgcn_mfma_f32_16x16x32_f16(vloF, Bhi, accL, 0, 0, 0);
        }
    }

    {
        const float one_pa = 1.f + alpha;
        #pragma unroll
        for (int r = 0; r < 4; ++r) {
            const int row = ag * 4 + r;
            smx[0][row][bcol] = accP[r];
            smx[1][row][bcol] = accP[r] - one_pa * accL[r];
        }
    }
    __syncthreads();
    #pragma unroll
    for (int rr = 0; rr < 4; ++rr) {
        const int row = w * 4 + rr;
        float zp = smx[0][row][l];
        float mp = zp;
        for (int off = 32; off > 0; off >>= 1) mp = fmaxf(mp, __shfl_xor(mp, off));
        float ep = __expf(zp - mp);
        float sump = ep;
        for (int off = 32; off > 0; off >>= 1) sump += __shfl_xor(sump, off);
        float pp = ep / sump;

        float zn = smx[1][row][l];
        float mn = zn;
        for (int off = 32; off > 0; off >>= 1) mn = fmaxf(mn, __shfl_xor(mn, off));
        float en = __expf(zn - mn);
        float sumn = en;
        for (int off = 32; off > 0; off >>= 1) sumn += __shfl_xor(sumn, off);
        float pn = en / sumn;

        const size_t gi = (size_t)gi0 + row;
        out3[gi * 64 + l] = 0.5f * (pp - pn + emb[gi * 64 + l]);
    }
}

extern "C" void kernel_launch(void* const* d_in, const int* in_sizes, int n_in,
                              void* d_out, int out_size, void* d_ws, size_t ws_size,
                              hipStream_t stream)
{
    (void)in_sizes; (void)n_in; (void)out_size;
    const float* ori = (const float*)d_in[0];
    const float* sm  = (const float*)d_in[1];
    // d_in[2] processed_feature: unused; d_in[3] universal_re: unused (BETA=0)
    const float* W0s = (const float*)d_in[4];
    const float* b0s = (const float*)d_in[5];
    const float* W1s = (const float*)d_in[6];
    const float* b1s = (const float*)d_in[7];
    const float* W0l = (const float*)d_in[8];
    const float* b0l = (const float*)d_in[9];
    const float* W1l = (const float*)d_in[10];
    const float* b1l = (const float*)d_in[11];
    const float* W0h = (const float*)d_in[12];
    const float* b0h = (const float*)d_in[13];
    const float* W1h = (const float*)d_in[14];
    const float* b1h = (const float*)d_in[15];
    const float* amp = (const float*)d_in[16];
    const float* ahp = (const float*)d_in[17];

    float* out = (float*)d_out;                       // f32 output (ref dtype)
    float* ws = (float*)d_ws;
    float* emb = ws;                                  // NN*64 f32
    float* ut  = ws + (size_t)NN * DOUT;              // 64*NN f32 (u transposed)
    double* colsum = (double*)(ws + (size_t)2 * NN * DOUT);   // 64 f64
    unsigned int* mx = (unsigned int*)(ws + (size_t)2 * NN * DOUT + 128);
    float* scal = ws + (size_t)2 * NN * DOUT + 128 + 4;       // 3 f32
    size_t eh_off = (((size_t)2 * NN * DOUT + 128 + 8) + 15) & ~(size_t)15;
    _Float16* ehi = (_Float16*)(ws + eh_off);                 // NN*64 halves
    _Float16* elo = (_Float16*)(ws + eh_off + (size_t)NN * DOUT / 2);
    size_t wpk_off = eh_off + (size_t)NN * DOUT;              // after ehi+elo
    _Float16* wpk = (_Float16*)(ws + wpk_off);                // 688128 halves
    size_t R_off = (wpk_off + WPK_HALVES / 2 + 15) & ~(size_t)15;
    float* R = ws + R_off;

    // How many R rows fit in the remaining workspace?
    size_t ws_f = ws_size / 4;
    size_t avail = (ws_f > R_off) ? (ws_f - R_off) : 0;
    int sr = (int)((avail / NN) / 64) * 64;           // rows per strip, x64
    if (sr < 64) sr = 64;                              // minimal strip (1.5 MB)
    if (sr > NN) sr = NN;
    const int nstrips = (NN + sr - 1) / sr;

    hipMemsetAsync(mx, 0, 4, stream);
    pack_w_kernel<<<dim3(64, 6), 256, 0, stream>>>(W0l, W0s, W0h, W1l, W1s, W1h, wpk);
    mlp2_kernel<<<dim3(NN / 64, 3), 256, 0, stream>>>(
        ori, sm, wpk, b0l, b0s, b0h, b1l, b1s, b1h, amp, ahp, out, emb, ut);
    colsum_kernel<<<64, 256, 0, stream>>>(ut, colsum);
    emb_split_kernel<<<NN * DOUT / 8 / 64 / 4, 256, 0, stream>>>(emb, ehi, elo);

    float* out3 = out + (size_t)2 * NN * DOUT;
    if (nstrips == 1) {
        r_gemm_kernel<<<dim3(96, 96), 256, 0, stream>>>(ut, R, mx, 0, 1, 1, 1);
        finalize_kernel<<<1, 64, 0, stream>>>(colsum, mx, scal);
        prop3_kernel<<<NN / 16, 256, 0, stream>>>(R, emb, ehi, elo, scal, ahp, out3, 0);
    } else {
        r_gemm_kernel<<<dim3(96, 96), 256, 0, stream>>>(ut, R, mx, 0, 1, 0, 1);
        finalize_kernel<<<1, 64, 0, stream>>>(colsum, mx, scal);
        for (int s = 0; s < nstrips; ++s) {
            const int row0 = s * sr;
            const int rows = (NN - row0 < sr) ? (NN - row0) : sr;
            r_gemm_kernel<<<dim3(rows / 64, 96), 256, 0, stream>>>(
                ut, R, mx, row0, 0, 1, 0);
            prop3_kernel<<<rows / 16, 256, 0, stream>>>(
                R, emb, ehi, elo, scal, ahp, out3, row0);
        }
    }
}